// Round 17
// baseline (1075.826 us; speedup 1.0000x reference)
//
#include <hip/hip_runtime.h>
#include <hip/hip_bf16.h>
#include <math.h>

#define BB 16
#define TT 360
#define VV 25
#define NN 9000
#define EE 72000
#define HH 128
#define RR (NN * BB)     // 144000 rows total
#define CROWS 18000      // rows per chunk (9000 nodes x 2 batches)
#define TPC2 282         // 64-row tiles per chunk (last tile: 16 valid rows)
#define NT3 (8 * TPC2)   // 2256 chunk-aligned tiles
#define NPART0 563       // partial-stats blocks for k_mm2 (L0)
#define NCLSS 12
#define EPSB 1e-5f

// chunked activation layout: row R(n,b) = (b>>1)*CROWS + n*2 + (b&1)

typedef _Float16 h8v __attribute__((ext_vector_type(8)));
typedef float float16v __attribute__((ext_vector_type(16)));

__device__ __forceinline__ h8v cf8(unsigned packed) {
    uint4 cc = {packed, packed, packed, packed};
    return __builtin_bit_cast(h8v, cc);
}

// ---------------- graph preprocessing ----------------

__global__ void k_count(const int* __restrict__ ei, int* __restrict__ counts) {
    int e = blockIdx.x * 256 + threadIdx.x;
    if (e < EE) atomicAdd(&counts[ei[EE + e]], 1);
}

__global__ void k_dinv(const int* __restrict__ counts, float* __restrict__ dinv,
                       unsigned* __restrict__ d2p) {
    int n = blockIdx.x * 256 + threadIdx.x;
    if (n >= NN) return;
    float di = rsqrtf((float)(counts[n] + 1));
    dinv[n] = di;
    _Float16 d2 = (_Float16)(di * di);
    unsigned short u = __builtin_bit_cast(unsigned short, d2);
    d2p[n] = (unsigned)u | ((unsigned)u << 16);
}

__global__ void k_scan(const int* __restrict__ counts, int* __restrict__ rowptr4) {
    __shared__ int part[1024];
    int t = threadIdx.x;
    int base = t * 9;
    int loc[9];
    int s = 0;
#pragma unroll
    for (int i = 0; i < 9; i++) {
        int idx = base + i;
        int v = (idx < NN) ? ((counts[idx] + 3) & ~3) : 0;
        loc[i] = s;
        s += v;
    }
    part[t] = s;
    __syncthreads();
    for (int d = 1; d < 1024; d <<= 1) {
        int v = (t >= d) ? part[t - d] : 0;
        __syncthreads();
        part[t] += v;
        __syncthreads();
    }
    int excl = (t == 0) ? 0 : part[t - 1];
#pragma unroll
    for (int i = 0; i < 9; i++) {
        int idx = base + i;
        if (idx < NN) rowptr4[idx] = excl + loc[i];
    }
    if (t == 1023) rowptr4[NN] = part[1023];
}

__global__ void k_fill(const int* __restrict__ ei, const int* __restrict__ rowptr4,
                       int* __restrict__ cursor, const float* __restrict__ dinv,
                       int2* __restrict__ csr) {
    int e = blockIdx.x * 256 + threadIdx.x;
    if (e >= EE) return;
    int s = ei[e], d = ei[EE + e];
    int slot = rowptr4[d] + atomicAdd(&cursor[d], 1);
    _Float16 cfh = (_Float16)(dinv[s] * dinv[d]);
    unsigned short u = __builtin_bit_cast(unsigned short, cfh);
    int2 e2;
    e2.x = s;
    e2.y = (int)((unsigned)u | ((unsigned)u << 16));
    csr[slot] = e2;
}

__global__ void k_pad(const int* __restrict__ rowptr4, const int* __restrict__ cursor,
                      int2* __restrict__ csr) {
    int n = blockIdx.x * 256 + threadIdx.x;
    if (n >= NN) return;
    int beg = rowptr4[n] + cursor[n];
    int end = rowptr4[n + 1];
    int2 z;
    z.x = n;
    z.y = 0;
    for (int e = beg; e < end; e++) csr[e] = z;
}

// pre-convert the 11 layer weight matrices to f16 W^T images: Wh[l][c*128+k]
__global__ void k_wcvt(const float* __restrict__ sW, const float* __restrict__ mW,
                       const float* __restrict__ aW, _Float16* __restrict__ Wh) {
    int idx = blockIdx.x * 256 + threadIdx.x;
    if (idx >= 11 * 16384) return;
    int l = idx >> 14, r = idx & 16383;
    int k = r >> 7, c = r & 127;
    const float* src = (l < 2) ? sW + (size_t)l * 16384
                               : ((l == 2) ? mW : aW + (size_t)(l - 3) * 16384);
    Wh[(size_t)l * 16384 + c * 128 + k] = (_Float16)src[k * 128 + c];
}

// ---------------- L0 propagation of raw x (2 channels, f32) ----------------
__global__ void k_prop2(const float* __restrict__ x, float* __restrict__ P0,
                        const int* __restrict__ rowptr4, const int2* __restrict__ csr,
                        const float* __restrict__ dinv) {
    int n = blockIdx.x * 256 + threadIdx.x;
    if (n >= NN) return;
    int b = blockIdx.y;
    const float* xb = x + (size_t)b * NN * 2;
    float d2 = dinv[n] * dinv[n];
    float a0 = d2 * xb[2 * n], a1 = d2 * xb[2 * n + 1];
    int beg = rowptr4[n], end = rowptr4[n + 1];
    for (int j = beg; j < end; j++) {
        int2 e2 = csr[j];
        int s = e2.x;
        unsigned short u = (unsigned short)((unsigned)e2.y & 0xffffu);
        float cf = (float)__builtin_bit_cast(_Float16, u);
        a0 += cf * xb[2 * s];
        a1 += cf * xb[2 * s + 1];
    }
    float* Pb = P0 + (size_t)(n * BB + b) * 2;
    Pb[0] = a0;
    Pb[1] = a1;
}

// L0 matmul (K=2), writes chunked f16 layout, fused BN partial stats pS[c][part].
__global__ void __launch_bounds__(256) k_mm2(const float* __restrict__ P0,
                                             _Float16* __restrict__ A,
                                             const float* __restrict__ W,
                                             const float* __restrict__ bias,
                                             float* __restrict__ pS1, float* __restrict__ pS2) {
    __shared__ float L1[256][8], L2[256][8];
    int t = threadIdx.x;
    int cg = t & 15, c8 = cg * 8;
    float wv0[8], wv1[8], bv[8];
#pragma unroll
    for (int j = 0; j < 8; j++) {
        wv0[j] = W[c8 + j];
        wv1[j] = W[HH + c8 + j];
        bv[j] = bias[c8 + j];
    }
    float s1[8], s2[8];
#pragma unroll
    for (int j = 0; j < 8; j++) { s1[j] = 0.f; s2[j] = 0.f; }
    for (int idx = blockIdx.x * 256 + t; idx < RR * 16; idx += gridDim.x * 256) {
        int Rr = idx >> 4;
        int q = Rr / CROWS;
        int rr = Rr - q * CROWS;
        int n = rr >> 1;
        int b = q * 2 + (rr & 1);
        float p0 = P0[((size_t)n * BB + b) * 2], p1 = P0[((size_t)n * BB + b) * 2 + 1];
        h8v o;
#pragma unroll
        for (int j = 0; j < 8; j++) {
            float v = p0 * wv0[j] + p1 * wv1[j] + bv[j];
            s1[j] += v;
            s2[j] += v * v;
            o[j] = (_Float16)v;
        }
        *(h8v*)(A + (size_t)Rr * HH + c8) = o;
    }
#pragma unroll
    for (int j = 0; j < 8; j++) { L1[t][j] = s1[j]; L2[t][j] = s2[j]; }
    __syncthreads();
    if (t < 16) {
#pragma unroll
        for (int g = 1; g < 16; g++)
#pragma unroll
            for (int j = 0; j < 8; j++) {
                s1[j] = (g == 1 ? L1[t][j] : s1[j]) + L1[t + 16 * g][j];
                s2[j] = (g == 1 ? L2[t][j] : s2[j]) + L2[t + 16 * g][j];
            }
#pragma unroll
        for (int j = 0; j < 8; j++) {
            pS1[(size_t)(t * 8 + j) * NPART0 + blockIdx.x] = s1[j];
            pS2[(size_t)(t * 8 + j) * NPART0 + blockIdx.x] = s2[j];
        }
    }
}

// ---------------- activation pass (L0 only): h' = relu(A*sc+sh) ----------------
__global__ void __launch_bounds__(256) k_act(const _Float16* __restrict__ A,
                                             _Float16* __restrict__ HP,
                                             const float* __restrict__ scale,
                                             const float* __restrict__ shiftv) {
    int i = blockIdx.x * 256 + threadIdx.x;
    int c8 = (i & 15) * 8;
    h8v v = *(const h8v*)(A + (size_t)i * 8);
    h8v o;
#pragma unroll
    for (int j = 0; j < 8; j++) {
        float f = (float)v[j] * scale[c8 + j] + shiftv[c8 + j];
        o[j] = (_Float16)fmaxf(f, 0.f);
    }
    *(h8v*)(HP + (size_t)i * 8) = o;
}

// ---------------- gather x NZ: P_z = A_hat * shift_z(h') (round-13 proven body) ----
__global__ void __launch_bounds__(256) k_gather3(const _Float16* __restrict__ h,
                                                 _Float16* B0, _Float16* B1, _Float16* B2,
                                                 const int* __restrict__ rowptr4,
                                                 const int2* __restrict__ csr,
                                                 const unsigned* __restrict__ d2p, int shbase) {
    int z = blockIdx.y;
    _Float16* Pz = (z == 0) ? B0 : ((z == 1) ? B1 : B2);
    int shn = shbase + z * 1000;
    int t = threadIdx.x;
    int q = blockIdx.x & 7;
    int ng4 = blockIdx.x >> 3;
    int wv = t >> 6, l = t & 63;
    int n = ng4 * 4 + wv;
    int half = l >> 5, li = l & 31;
    const _Float16* hb = h + (size_t)q * CROWS * HH + (size_t)li * 8;
    int pn = n + shn;
    if (pn >= NN) pn -= NN;
    h8v acc;
    {
        h8v v = *(const h8v*)(hb + (size_t)pn * 2 * HH);
        acc = v * cf8(half ? 0u : d2p[n]);
    }
    int beg = rowptr4[n], end = rowptr4[n + 1];
    int e = beg;
    for (; e + 8 <= end; e += 8) {
        int4 m0 = *(const int4*)(csr + e);
        int4 m1 = *(const int4*)(csr + e + 2);
        int4 m2 = *(const int4*)(csr + e + 4);
        int4 m3 = *(const int4*)(csr + e + 6);
        int s0 = (half ? m0.z : m0.x) + shn; if (s0 >= NN) s0 -= NN;
        int s1 = (half ? m1.z : m1.x) + shn; if (s1 >= NN) s1 -= NN;
        int s2 = (half ? m2.z : m2.x) + shn; if (s2 >= NN) s2 -= NN;
        int s3 = (half ? m3.z : m3.x) + shn; if (s3 >= NN) s3 -= NN;
        h8v v0 = *(const h8v*)(hb + (size_t)s0 * 2 * HH);
        h8v v1 = *(const h8v*)(hb + (size_t)s1 * 2 * HH);
        h8v v2 = *(const h8v*)(hb + (size_t)s2 * 2 * HH);
        h8v v3 = *(const h8v*)(hb + (size_t)s3 * 2 * HH);
        acc += v0 * cf8((unsigned)(half ? m0.w : m0.y));
        acc += v1 * cf8((unsigned)(half ? m1.w : m1.y));
        acc += v2 * cf8((unsigned)(half ? m2.w : m2.y));
        acc += v3 * cf8((unsigned)(half ? m3.w : m3.y));
    }
    if (e < end) {
        int4 m0 = *(const int4*)(csr + e);
        int4 m1 = *(const int4*)(csr + e + 2);
        int s0 = (half ? m0.z : m0.x) + shn; if (s0 >= NN) s0 -= NN;
        int s1 = (half ? m1.z : m1.x) + shn; if (s1 >= NN) s1 -= NN;
        h8v v0 = *(const h8v*)(hb + (size_t)s0 * 2 * HH);
        h8v v1 = *(const h8v*)(hb + (size_t)s1 * 2 * HH);
        acc += v0 * cf8((unsigned)(half ? m0.w : m0.y));
        acc += v1 * cf8((unsigned)(half ? m1.w : m1.y));
    }
    {
        int4 ai = __builtin_bit_cast(int4, acc);
        int4 bi4;
        bi4.x = __shfl_xor(ai.x, 32, 64);
        bi4.y = __shfl_xor(ai.y, 32, 64);
        bi4.z = __shfl_xor(ai.z, 32, 64);
        bi4.w = __shfl_xor(ai.w, 32, 64);
        acc += __builtin_bit_cast(h8v, bi4);
    }
    if (half == 0) {
        *(h8v*)(Pz + ((size_t)q * CROWS + (size_t)n * 2) * HH + (size_t)li * 8) = acc;
    }
}

// ---- MFMA core macro-ish helpers: chunk-aligned 64-row tiles, tail guarded ----
// tile decomposition shared by the three MFMA kernels below.

// stats-only pass: NO stores of A; partials pS[(z*HH+c)][NT3]
__global__ void __launch_bounds__(256) k_mfmaS3(const _Float16* B0, const _Float16* B1,
                                                const _Float16* B2,
                                                const _Float16* __restrict__ Wh_g,
                                                const float* bias0, const float* bias1,
                                                const float* bias2,
                                                float* __restrict__ pS1,
                                                float* __restrict__ pS2) {
    __shared__ float rb1[4][128], rb2[4][128];
    int z = blockIdx.y;
    const _Float16* B = (z == 0) ? B0 : ((z == 1) ? B1 : B2);
    const _Float16* Wh = Wh_g + (size_t)z * 16384;
    const float* bias = (z == 0) ? bias0 : ((z == 1) ? bias1 : bias2);
    int t = threadIdx.x;
    int w = t >> 6, l = t & 63;
    int rw = w >> 1, cw = w & 1;
    int lr = l & 31, hi = l >> 5;
    int q = blockIdx.x / TPC2, tile = blockIdx.x - q * TPC2;
    int vrows = CROWS - tile * 64;
    if (vrows > 64) vrows = 64;
    size_t rbase = (size_t)q * CROWS + (size_t)tile * 64;
    const _Float16* Pr0 = B + (rbase + rw * 32 + lr) * HH;
    const _Float16* Wc0 = Wh + (size_t)(cw * 64 + lr) * HH;
    const _Float16* Wc1 = Wh + (size_t)(cw * 64 + 32 + lr) * HH;
    float16v acc2[2];
#pragma unroll
    for (int ct = 0; ct < 2; ct++) acc2[ct] = (float16v)(0.0f);
#pragma unroll
    for (int ks = 0; ks < 8; ks++) {
        int koff = ks * 16 + hi * 8;
        h8v a0 = *(const h8v*)(Pr0 + koff);
        h8v b0 = *(const h8v*)(Wc0 + koff);
        h8v b1 = *(const h8v*)(Wc1 + koff);
        acc2[0] = __builtin_amdgcn_mfma_f32_32x32x16_f16(a0, b0, acc2[0], 0, 0, 0);
        acc2[1] = __builtin_amdgcn_mfma_f32_32x32x16_f16(a0, b1, acc2[1], 0, 0, 0);
    }
    float bv[2] = {bias[cw * 64 + lr], bias[cw * 64 + 32 + lr]};
    float s1a[2] = {0.f, 0.f}, s2a[2] = {0.f, 0.f};
#pragma unroll
    for (int ct = 0; ct < 2; ct++) {
#pragma unroll
        for (int g = 0; g < 16; g++) {
            int row = rw * 32 + (g & 3) + 8 * (g >> 2) + 4 * hi;
            if (row < vrows) {
                float v = acc2[ct][g] + bv[ct];
                s1a[ct] += v;
                s2a[ct] += v * v;
            }
        }
    }
    int slot = rw * 2 + hi;
#pragma unroll
    for (int ct = 0; ct < 2; ct++) {
        int cidx = cw * 64 + ct * 32 + lr;
        rb1[slot][cidx] = s1a[ct];
        rb2[slot][cidx] = s2a[ct];
    }
    __syncthreads();
    if (t < 128) {
        float a1 = rb1[0][t] + rb1[1][t] + rb1[2][t] + rb1[3][t];
        float a2 = rb2[0][t] + rb2[1][t] + rb2[2][t] + rb2[3][t];
        pS1[((size_t)z * HH + t) * NT3 + blockIdx.x] = a1;
        pS2[((size_t)z * HH + t) * NT3 + blockIdx.x] = a2;
    }
}

// trunk recompute pass: A recomputed, affine+relu applied, written to HP (activated)
__global__ void __launch_bounds__(256) k_mfmaA(const _Float16* __restrict__ B,
                                               const _Float16* __restrict__ Wh,
                                               const float* __restrict__ bias,
                                               const float* __restrict__ scale,
                                               const float* __restrict__ shiftv,
                                               _Float16* __restrict__ HP) {
    int t = threadIdx.x;
    int w = t >> 6, l = t & 63;
    int rw = w >> 1, cw = w & 1;
    int lr = l & 31, hi = l >> 5;
    int q = blockIdx.x / TPC2, tile = blockIdx.x - q * TPC2;
    int vrows = CROWS - tile * 64;
    if (vrows > 64) vrows = 64;
    size_t rbase = (size_t)q * CROWS + (size_t)tile * 64;
    const _Float16* Pr0 = B + (rbase + rw * 32 + lr) * HH;
    const _Float16* Wc0 = Wh + (size_t)(cw * 64 + lr) * HH;
    const _Float16* Wc1 = Wh + (size_t)(cw * 64 + 32 + lr) * HH;
    float16v acc2[2];
#pragma unroll
    for (int ct = 0; ct < 2; ct++) acc2[ct] = (float16v)(0.0f);
#pragma unroll
    for (int ks = 0; ks < 8; ks++) {
        int koff = ks * 16 + hi * 8;
        h8v a0 = *(const h8v*)(Pr0 + koff);
        h8v b0 = *(const h8v*)(Wc0 + koff);
        h8v b1 = *(const h8v*)(Wc1 + koff);
        acc2[0] = __builtin_amdgcn_mfma_f32_32x32x16_f16(a0, b0, acc2[0], 0, 0, 0);
        acc2[1] = __builtin_amdgcn_mfma_f32_32x32x16_f16(a0, b1, acc2[1], 0, 0, 0);
    }
#pragma unroll
    for (int ct = 0; ct < 2; ct++) {
        int c = cw * 64 + ct * 32 + lr;
        float bv = bias[c];
        float sc = scale[c], sh = shiftv[c];
#pragma unroll
        for (int g = 0; g < 16; g++) {
            int row = rw * 32 + (g & 3) + 8 * (g >> 2) + 4 * hi;
            if (row < vrows) {
                float v = (acc2[ct][g] + bv) * sc + sh;
                HP[(rbase + row) * HH + c] = (_Float16)fmaxf(v, 0.f);
            }
        }
    }
}

// head recompute pass: A recomputed, affine+relu, pooled directly (no A store)
__global__ void __launch_bounds__(256) k_mfmaP3(const _Float16* B0, const _Float16* B1,
                                                const _Float16* B2,
                                                const _Float16* __restrict__ Wh_g,
                                                const float* bias0, const float* bias1,
                                                const float* bias2,
                                                const float* __restrict__ scale,
                                                const float* __restrict__ shiftv,
                                                float* __restrict__ pooled) {
    __shared__ float rbP[2][4][128];
    int z = blockIdx.y;
    const _Float16* B = (z == 0) ? B0 : ((z == 1) ? B1 : B2);
    const _Float16* Wh = Wh_g + (size_t)z * 16384;
    const float* bias = (z == 0) ? bias0 : ((z == 1) ? bias1 : bias2);
    const float* sc0 = scale + z * HH;
    const float* sh0 = shiftv + z * HH;
    float* pz = pooled + (size_t)z * BB * HH;
    int t = threadIdx.x;
    int w = t >> 6, l = t & 63;
    int rw = w >> 1, cw = w & 1;
    int lr = l & 31, hi = l >> 5;
    int q = blockIdx.x / TPC2, tile = blockIdx.x - q * TPC2;
    int vrows = CROWS - tile * 64;
    if (vrows > 64) vrows = 64;
    size_t rbase = (size_t)q * CROWS + (size_t)tile * 64;
    const _Float16* Pr0 = B + (rbase + rw * 32 + lr) * HH;
    const _Float16* Wc0 = Wh + (size_t)(cw * 64 + lr) * HH;
    const _Float16* Wc1 = Wh + (size_t)(cw * 64 + 32 + lr) * HH;
    float16v acc2[2];
#pragma unroll
    for (int ct = 0; ct < 2; ct++) acc2[ct] = (float16v)(0.0f);
#pragma unroll
    for (int ks = 0; ks < 8; ks++) {
        int koff = ks * 16 + hi * 8;
        h8v a0 = *(const h8v*)(Pr0 + koff);
        h8v b0 = *(const h8v*)(Wc0 + koff);
        h8v b1 = *(const h8v*)(Wc1 + koff);
        acc2[0] = __builtin_amdgcn_mfma_f32_32x32x16_f16(a0, b0, acc2[0], 0, 0, 0);
        acc2[1] = __builtin_amdgcn_mfma_f32_32x32x16_f16(a0, b1, acc2[1], 0, 0, 0);
    }
    // per-thread pool partials, split by row parity (= batch-in-chunk)
    float pp[2][2] = {{0.f, 0.f}, {0.f, 0.f}};  // [ct][parity] -- static indexing below
#pragma unroll
    for (int ct = 0; ct < 2; ct++) {
        int c = cw * 64 + ct * 32 + lr;
        float bv = bias[c];
        float sc = sc0[c], sh = sh0[c];
#pragma unroll
        for (int g = 0; g < 16; g++) {
            int row = rw * 32 + (g & 3) + 8 * (g >> 2) + 4 * hi;
            if (row < vrows) {
                float v = (acc2[ct][g] + bv) * sc + sh;
                float f = fmaxf(v, 0.f);
                if (g & 1) pp[ct][1] += f; else pp[ct][0] += f;
            }
        }
    }
    int slot = rw * 2 + hi;
#pragma unroll
    for (int ct = 0; ct < 2; ct++) {
        int cidx = cw * 64 + ct * 32 + lr;
        rbP[0][slot][cidx] = pp[ct][0];
        rbP[1][slot][cidx] = pp[ct][1];
    }
    __syncthreads();
    if (t < 256 && (t >> 7) < 2) {
        int par = t >> 7, c = t & 127;
        float a = rbP[par][0][c] + rbP[par][1][c] + rbP[par][2][c] + rbP[par][3][c];
        atomicAdd(&pz[(q * 2 + par) * HH + c], a);
    }
}

// finalize BN affine from transposed partials, grid = NZ*128 blocks
__global__ void __launch_bounds__(256) k_bnfin3(const float* __restrict__ pS1,
                                                const float* __restrict__ pS2, int npart,
                                                const float* g0, const float* g1,
                                                const float* g2, const float* be0,
                                                const float* be1, const float* be2,
                                                float* __restrict__ scale,
                                                float* __restrict__ shiftv) {
    __shared__ float R1[256], R2[256];
    int z = blockIdx.x >> 7, c = blockIdx.x & 127;
    const float* g = (z == 0) ? g0 : ((z == 1) ? g1 : g2);
    const float* be = (z == 0) ? be0 : ((z == 1) ? be1 : be2);
    int t = threadIdx.x;
    const float* p1 = pS1 + ((size_t)z * HH + c) * npart;
    const float* p2 = pS2 + ((size_t)z * HH + c) * npart;
    float s1 = 0.f, s2 = 0.f;
    for (int i = t; i < npart; i += 256) {
        s1 += p1[i];
        s2 += p2[i];
    }
    R1[t] = s1;
    R2[t] = s2;
    __syncthreads();
    for (int d = 128; d > 0; d >>= 1) {
        if (t < d) {
            R1[t] += R1[t + d];
            R2[t] += R2[t + d];
        }
        __syncthreads();
    }
    if (t == 0) {
        float inv = 1.0f / (float)RR;
        float mu = R1[0] * inv;
        float var = R2[0] * inv - mu * mu;
        float sc = g[c] * rsqrtf(var + EPSB);
        scale[z * HH + c] = sc;
        shiftv[z * HH + c] = be[c] - mu * sc;
    }
}

// all 9 heads: linear + log_softmax
__global__ void __launch_bounds__(192) k_head_all(const float* __restrict__ pooled,
                                                  const float* __restrict__ main_Wf,
                                                  const float* __restrict__ main_bf,
                                                  const float* __restrict__ aux_Wf,
                                                  const float* __restrict__ aux_bf,
                                                  float* __restrict__ out) {
    int hd = blockIdx.x;
    const float* Wf = hd ? aux_Wf + (size_t)(hd - 1) * HH * NCLSS : main_Wf;
    const float* bf = hd ? aux_bf + (hd - 1) * NCLSS : main_bf;
    const float* pl = pooled + (size_t)hd * BB * HH;
    __shared__ float z[BB][NCLSS];
    __shared__ float lse[BB];
    int t = threadIdx.x;
    int b = t / NCLSS, j = t % NCLSS;
    if (t < BB * NCLSS) {
        float acc = bf[j];
        const float invn = 1.0f / NN;
        for (int c = 0; c < HH; c++) acc += pl[b * HH + c] * invn * Wf[c * NCLSS + j];
        z[b][j] = acc;
    }
    __syncthreads();
    if (t < BB) {
        float m = -1e30f;
        for (int j2 = 0; j2 < NCLSS; j2++) m = fmaxf(m, z[t][j2]);
        float s = 0.f;
        for (int j2 = 0; j2 < NCLSS; j2++) s += expf(z[t][j2] - m);
        lse[t] = m + logf(s);
    }
    __syncthreads();
    if (t < BB * NCLSS) {
        float* o = hd ? out + BB * NCLSS + ((size_t)b * 8 + (hd - 1)) * NCLSS + j
                      : out + b * NCLSS + j;
        *o = z[b][j] - lse[b];
    }
}

// ---------------- host ----------------

extern "C" void kernel_launch(void* const* d_in, const int* in_sizes, int n_in, void* d_out,
                              int out_size, void* d_ws, size_t ws_size, hipStream_t stream) {
    const float* x = (const float*)d_in[0];
    const int* ei = (const int*)d_in[1];
    const float* W_in = (const float*)d_in[2];
    const float* b_in = (const float*)d_in[3];
    const float* g_in = (const float*)d_in[4];
    const float* be_in = (const float*)d_in[5];
    const float* shared_W = (const float*)d_in[6];
    const float* shared_b = (const float*)d_in[7];
    const float* shared_g = (const float*)d_in[8];
    const float* shared_be = (const float*)d_in[9];
    const float* main_Wg = (const float*)d_in[10];
    const float* main_bg = (const float*)d_in[11];
    const float* main_g = (const float*)d_in[12];
    const float* main_be = (const float*)d_in[13];
    const float* main_Wf = (const float*)d_in[14];
    const float* main_bf = (const float*)d_in[15];
    const float* aux_Wg = (const float*)d_in[16];
    const float* aux_bg = (const float*)d_in[17];
    const float* aux_g = (const float*)d_in[18];
    const float* aux_be = (const float*)d_in[19];
    const float* aux_Wf = (const float*)d_in[20];
    const float* aux_bf = (const float*)d_in[21];
    float* out = (float*)d_out;

    char* w = (char*)d_ws;
    const size_t BIG = (size_t)RR * HH * 2;
    _Float16* U = (_Float16*)w;  w += BIG;
    _Float16* V = (_Float16*)w;  w += BIG;
    _Float16* P = (_Float16*)w;  w += BIG;
    _Float16* HP = (_Float16*)w; w += BIG;
    float* P0 = (float*)w;       w += (size_t)RR * 2 * 4;
    _Float16* Wh = (_Float16*)w; w += (size_t)11 * 16384 * 2;
    int2* csr = (int2*)w;        w += (size_t)102400 * 8;
    int* counts = (int*)w;       w += NN * 4;
    int* cursor = (int*)w;       w += NN * 4;
    float* dinv = (float*)w;     w += NN * 4;
    unsigned* d2p = (unsigned*)w; w += NN * 4;
    int* rowptr4 = (int*)w;      w += 36016;
    float* pS1 = (float*)w;      w += (size_t)3 * HH * NT3 * 4;
    float* pS2 = (float*)w;      w += (size_t)3 * HH * NT3 * 4;
    float* pooled = (float*)w;   w += 9 * BB * HH * 4;
    float* tscale = (float*)w;   w += 512;
    float* tshift = (float*)w;   w += 512;
    float* hscale = (float*)w;   w += 2048;
    float* hshift = (float*)w;   w += 2048;

    hipMemsetAsync(counts, 0, 2 * NN * 4, stream);
    hipMemsetAsync(pooled, 0, 9 * BB * HH * 4, stream);

    k_count<<<(EE + 255) / 256, 256, 0, stream>>>(ei, counts);
    k_dinv<<<(NN + 255) / 256, 256, 0, stream>>>(counts, dinv, d2p);
    k_scan<<<1, 1024, 0, stream>>>(counts, rowptr4);
    k_fill<<<(EE + 255) / 256, 256, 0, stream>>>(ei, rowptr4, cursor, dinv, csr);
    k_pad<<<(NN + 255) / 256, 256, 0, stream>>>(rowptr4, cursor, csr);
    k_wcvt<<<(11 * 16384 + 255) / 256, 256, 0, stream>>>(shared_W, main_Wg, aux_Wg, Wh);

    // L0: prop x, K=2 matmul -> U (pre-BN), stats -> tscale/tshift, act -> HP
    {
        dim3 g((NN + 255) / 256, BB);
        k_prop2<<<g, 256, 0, stream>>>(x, P0, rowptr4, csr, dinv);
        k_mm2<<<NPART0, 256, 0, stream>>>(P0, U, W_in, b_in, pS1, pS2);
        k_bnfin3<<<HH, 256, 0, stream>>>(pS1, pS2, NPART0, g_in, g_in, g_in, be_in, be_in,
                                         be_in, tscale, tshift);
        k_act<<<RR * 16 / 256, 256, 0, stream>>>(U, HP, tscale, tshift);
    }

    // trunk layers: gather(HP->V), statsMFMA(V), bnfin, recomputeMFMA+act(V)->HP
    for (int l = 0; l < 2; l++) {
        k_gather3<<<dim3(8 * 2250, 1), 256, 0, stream>>>(HP, V, V, V, rowptr4, csr, d2p, 0);
        k_mfmaS3<<<dim3(NT3, 1), 256, 0, stream>>>(V, V, V, Wh + (size_t)l * 16384,
                                                   shared_b + l * HH, shared_b + l * HH,
                                                   shared_b + l * HH, pS1, pS2);
        k_bnfin3<<<HH, 256, 0, stream>>>(pS1, pS2, NT3, shared_g + l * HH, shared_g + l * HH,
                                         shared_g + l * HH, shared_be + l * HH,
                                         shared_be + l * HH, shared_be + l * HH, tscale, tshift);
        k_mfmaA<<<NT3, 256, 0, stream>>>(V, Wh + (size_t)l * 16384, shared_b + l * HH, tscale,
                                         tshift, HP);
    }

    // heads in 3 groups of 3: gather -> statsMFMA -> bnfin -> recomputeMFMA+pool
    for (int g = 0; g < 3; g++) {
        int h0 = g * 3;
        const float* bg[3];
        const float* gg[3];
        const float* be[3];
        for (int z = 0; z < 3; z++) {
            int hd = h0 + z;
            bg[z] = (hd == 0) ? main_bg : aux_bg + (hd - 1) * HH;
            gg[z] = (hd == 0) ? main_g : aux_g + (hd - 1) * HH;
            be[z] = (hd == 0) ? main_be : aux_be + (hd - 1) * HH;
        }
        k_gather3<<<dim3(8 * 2250, 3), 256, 0, stream>>>(HP, P, U, V, rowptr4, csr, d2p,
                                                         h0 * 1000);
        k_mfmaS3<<<dim3(NT3, 3), 256, 0, stream>>>(P, U, V, Wh + (size_t)(2 + h0) * 16384,
                                                   bg[0], bg[1], bg[2], pS1, pS2);
        k_bnfin3<<<3 * HH, 256, 0, stream>>>(pS1, pS2, NT3, gg[0], gg[1], gg[2], be[0], be[1],
                                             be[2], hscale, hshift);
        k_mfmaP3<<<dim3(NT3, 3), 256, 0, stream>>>(P, U, V, Wh + (size_t)(2 + h0) * 16384,
                                                   bg[0], bg[1], bg[2], hscale, hshift,
                                                   pooled + (size_t)h0 * BB * HH);
    }
    k_head_all<<<9, 192, 0, stream>>>(pooled, main_Wf, main_bf, aux_Wf, aux_bf, out);
}

// Round 18
// 930.581 us; speedup vs baseline: 1.1561x; 1.1561x over previous
//
#include <hip/hip_runtime.h>
#include <hip/hip_bf16.h>
#include <math.h>

#define BB 16
#define TT 360
#define VV 25
#define NN 9000
#define EE 72000
#define HH 128
#define RR (NN * BB)     // 144000 rows total
#define CROWS 18000      // rows per chunk (9000 nodes x 2 batches)
#define TPC2 282         // 64-row tiles per chunk (last tile: 16 valid rows)
#define NT3 (8 * TPC2)   // 2256 chunk-aligned tiles
#define NPART0 563       // partial-stats blocks for k_mm2 (L0)
#define NCLSS 12
#define EPSB 1e-5f

// chunked activation layout: row R(n,b) = (b>>1)*CROWS + n*2 + (b&1)

typedef _Float16 h8v __attribute__((ext_vector_type(8)));
typedef float float16v __attribute__((ext_vector_type(16)));

__device__ __forceinline__ h8v cf8(unsigned packed) {
    uint4 cc = {packed, packed, packed, packed};
    return __builtin_bit_cast(h8v, cc);
}

// ---------------- graph preprocessing ----------------

__global__ void k_count(const int* __restrict__ ei, int* __restrict__ counts) {
    int e = blockIdx.x * 256 + threadIdx.x;
    if (e < EE) atomicAdd(&counts[ei[EE + e]], 1);
}

__global__ void k_dinv(const int* __restrict__ counts, float* __restrict__ dinv,
                       unsigned* __restrict__ d2p) {
    int n = blockIdx.x * 256 + threadIdx.x;
    if (n >= NN) return;
    float di = rsqrtf((float)(counts[n] + 1));
    dinv[n] = di;
    _Float16 d2 = (_Float16)(di * di);
    unsigned short u = __builtin_bit_cast(unsigned short, d2);
    d2p[n] = (unsigned)u | ((unsigned)u << 16);
}

__global__ void k_scan(const int* __restrict__ counts, int* __restrict__ rowptr4) {
    __shared__ int part[1024];
    int t = threadIdx.x;
    int base = t * 9;
    int loc[9];
    int s = 0;
#pragma unroll
    for (int i = 0; i < 9; i++) {
        int idx = base + i;
        int v = (idx < NN) ? ((counts[idx] + 3) & ~3) : 0;
        loc[i] = s;
        s += v;
    }
    part[t] = s;
    __syncthreads();
    for (int d = 1; d < 1024; d <<= 1) {
        int v = (t >= d) ? part[t - d] : 0;
        __syncthreads();
        part[t] += v;
        __syncthreads();
    }
    int excl = (t == 0) ? 0 : part[t - 1];
#pragma unroll
    for (int i = 0; i < 9; i++) {
        int idx = base + i;
        if (idx < NN) rowptr4[idx] = excl + loc[i];
    }
    if (t == 1023) rowptr4[NN] = part[1023];
}

__global__ void k_fill(const int* __restrict__ ei, const int* __restrict__ rowptr4,
                       int* __restrict__ cursor, const float* __restrict__ dinv,
                       int2* __restrict__ csr) {
    int e = blockIdx.x * 256 + threadIdx.x;
    if (e >= EE) return;
    int s = ei[e], d = ei[EE + e];
    int slot = rowptr4[d] + atomicAdd(&cursor[d], 1);
    _Float16 cfh = (_Float16)(dinv[s] * dinv[d]);
    unsigned short u = __builtin_bit_cast(unsigned short, cfh);
    int2 e2;
    e2.x = s;
    e2.y = (int)((unsigned)u | ((unsigned)u << 16));
    csr[slot] = e2;
}

__global__ void k_pad(const int* __restrict__ rowptr4, const int* __restrict__ cursor,
                      int2* __restrict__ csr) {
    int n = blockIdx.x * 256 + threadIdx.x;
    if (n >= NN) return;
    int beg = rowptr4[n] + cursor[n];
    int end = rowptr4[n + 1];
    int2 z;
    z.x = n;
    z.y = 0;
    for (int e = beg; e < end; e++) csr[e] = z;
}

// pre-convert the 11 layer weight matrices to f16 W^T images: Wh[l][c*128+k]
__global__ void k_wcvt(const float* __restrict__ sW, const float* __restrict__ mW,
                       const float* __restrict__ aW, _Float16* __restrict__ Wh) {
    int idx = blockIdx.x * 256 + threadIdx.x;
    if (idx >= 11 * 16384) return;
    int l = idx >> 14, r = idx & 16383;
    int k = r >> 7, c = r & 127;
    const float* src = (l < 2) ? sW + (size_t)l * 16384
                               : ((l == 2) ? mW : aW + (size_t)(l - 3) * 16384);
    Wh[(size_t)l * 16384 + c * 128 + k] = (_Float16)src[k * 128 + c];
}

// ---------------- L0 propagation of raw x (2 channels, f32) ----------------
__global__ void k_prop2(const float* __restrict__ x, float* __restrict__ P0,
                        const int* __restrict__ rowptr4, const int2* __restrict__ csr,
                        const float* __restrict__ dinv) {
    int n = blockIdx.x * 256 + threadIdx.x;
    if (n >= NN) return;
    int b = blockIdx.y;
    const float* xb = x + (size_t)b * NN * 2;
    float d2 = dinv[n] * dinv[n];
    float a0 = d2 * xb[2 * n], a1 = d2 * xb[2 * n + 1];
    int beg = rowptr4[n], end = rowptr4[n + 1];
    for (int j = beg; j < end; j++) {
        int2 e2 = csr[j];
        int s = e2.x;
        unsigned short u = (unsigned short)((unsigned)e2.y & 0xffffu);
        float cf = (float)__builtin_bit_cast(_Float16, u);
        a0 += cf * xb[2 * s];
        a1 += cf * xb[2 * s + 1];
    }
    float* Pb = P0 + (size_t)(n * BB + b) * 2;
    Pb[0] = a0;
    Pb[1] = a1;
}

// L0 matmul (K=2), writes chunked f16 layout, fused BN partial stats pS[c][part].
__global__ void __launch_bounds__(256) k_mm2(const float* __restrict__ P0,
                                             _Float16* __restrict__ A,
                                             const float* __restrict__ W,
                                             const float* __restrict__ bias,
                                             float* __restrict__ pS1, float* __restrict__ pS2) {
    __shared__ float L1[256][8], L2[256][8];
    int t = threadIdx.x;
    int cg = t & 15, c8 = cg * 8;
    float wv0[8], wv1[8], bv[8];
#pragma unroll
    for (int j = 0; j < 8; j++) {
        wv0[j] = W[c8 + j];
        wv1[j] = W[HH + c8 + j];
        bv[j] = bias[c8 + j];
    }
    float s1[8], s2[8];
#pragma unroll
    for (int j = 0; j < 8; j++) { s1[j] = 0.f; s2[j] = 0.f; }
    for (int idx = blockIdx.x * 256 + t; idx < RR * 16; idx += gridDim.x * 256) {
        int Rr = idx >> 4;
        int q = Rr / CROWS;
        int rr = Rr - q * CROWS;
        int n = rr >> 1;
        int b = q * 2 + (rr & 1);
        float p0 = P0[((size_t)n * BB + b) * 2], p1 = P0[((size_t)n * BB + b) * 2 + 1];
        h8v o;
#pragma unroll
        for (int j = 0; j < 8; j++) {
            float v = p0 * wv0[j] + p1 * wv1[j] + bv[j];
            s1[j] += v;
            s2[j] += v * v;
            o[j] = (_Float16)v;
        }
        *(h8v*)(A + (size_t)Rr * HH + c8) = o;
    }
#pragma unroll
    for (int j = 0; j < 8; j++) { L1[t][j] = s1[j]; L2[t][j] = s2[j]; }
    __syncthreads();
    if (t < 16) {
#pragma unroll
        for (int g = 1; g < 16; g++)
#pragma unroll
            for (int j = 0; j < 8; j++) {
                s1[j] = (g == 1 ? L1[t][j] : s1[j]) + L1[t + 16 * g][j];
                s2[j] = (g == 1 ? L2[t][j] : s2[j]) + L2[t + 16 * g][j];
            }
#pragma unroll
        for (int j = 0; j < 8; j++) {
            pS1[(size_t)(t * 8 + j) * NPART0 + blockIdx.x] = s1[j];
            pS2[(size_t)(t * 8 + j) * NPART0 + blockIdx.x] = s2[j];
        }
    }
}

// ---------------- activation pass: h' = relu(A*sc+sh), f16 -> f16 ----------------
__global__ void __launch_bounds__(256) k_act(const _Float16* __restrict__ A,
                                             _Float16* __restrict__ HP,
                                             const float* __restrict__ scale,
                                             const float* __restrict__ shiftv) {
    int i = blockIdx.x * 256 + threadIdx.x;
    int c8 = (i & 15) * 8;
    h8v v = *(const h8v*)(A + (size_t)i * 8);
    h8v o;
#pragma unroll
    for (int j = 0; j < 8; j++) {
        float f = (float)v[j] * scale[c8 + j] + shiftv[c8 + j];
        o[j] = (_Float16)fmaxf(f, 0.f);
    }
    *(h8v*)(HP + (size_t)i * 8) = o;
}

// ---------------- gather x NZ: P_z = A_hat * shift_z(h') (round-13 proven body) ----
__global__ void __launch_bounds__(256) k_gather3(const _Float16* __restrict__ h,
                                                 _Float16* B0, _Float16* B1, _Float16* B2,
                                                 const int* __restrict__ rowptr4,
                                                 const int2* __restrict__ csr,
                                                 const unsigned* __restrict__ d2p, int shbase) {
    int z = blockIdx.y;
    _Float16* Pz = (z == 0) ? B0 : ((z == 1) ? B1 : B2);
    int shn = shbase + z * 1000;
    int t = threadIdx.x;
    int q = blockIdx.x & 7;
    int ng4 = blockIdx.x >> 3;
    int wv = t >> 6, l = t & 63;
    int n = ng4 * 4 + wv;
    int half = l >> 5, li = l & 31;
    const _Float16* hb = h + (size_t)q * CROWS * HH + (size_t)li * 8;
    int pn = n + shn;
    if (pn >= NN) pn -= NN;
    h8v acc;
    {
        h8v v = *(const h8v*)(hb + (size_t)pn * 2 * HH);
        acc = v * cf8(half ? 0u : d2p[n]);
    }
    int beg = rowptr4[n], end = rowptr4[n + 1];
    int e = beg;
    for (; e + 8 <= end; e += 8) {
        int4 m0 = *(const int4*)(csr + e);
        int4 m1 = *(const int4*)(csr + e + 2);
        int4 m2 = *(const int4*)(csr + e + 4);
        int4 m3 = *(const int4*)(csr + e + 6);
        int s0 = (half ? m0.z : m0.x) + shn; if (s0 >= NN) s0 -= NN;
        int s1 = (half ? m1.z : m1.x) + shn; if (s1 >= NN) s1 -= NN;
        int s2 = (half ? m2.z : m2.x) + shn; if (s2 >= NN) s2 -= NN;
        int s3 = (half ? m3.z : m3.x) + shn; if (s3 >= NN) s3 -= NN;
        h8v v0 = *(const h8v*)(hb + (size_t)s0 * 2 * HH);
        h8v v1 = *(const h8v*)(hb + (size_t)s1 * 2 * HH);
        h8v v2 = *(const h8v*)(hb + (size_t)s2 * 2 * HH);
        h8v v3 = *(const h8v*)(hb + (size_t)s3 * 2 * HH);
        acc += v0 * cf8((unsigned)(half ? m0.w : m0.y));
        acc += v1 * cf8((unsigned)(half ? m1.w : m1.y));
        acc += v2 * cf8((unsigned)(half ? m2.w : m2.y));
        acc += v3 * cf8((unsigned)(half ? m3.w : m3.y));
    }
    if (e < end) {
        int4 m0 = *(const int4*)(csr + e);
        int4 m1 = *(const int4*)(csr + e + 2);
        int s0 = (half ? m0.z : m0.x) + shn; if (s0 >= NN) s0 -= NN;
        int s1 = (half ? m1.z : m1.x) + shn; if (s1 >= NN) s1 -= NN;
        h8v v0 = *(const h8v*)(hb + (size_t)s0 * 2 * HH);
        h8v v1 = *(const h8v*)(hb + (size_t)s1 * 2 * HH);
        acc += v0 * cf8((unsigned)(half ? m0.w : m0.y));
        acc += v1 * cf8((unsigned)(half ? m1.w : m1.y));
    }
    {
        int4 ai = __builtin_bit_cast(int4, acc);
        int4 bi4;
        bi4.x = __shfl_xor(ai.x, 32, 64);
        bi4.y = __shfl_xor(ai.y, 32, 64);
        bi4.z = __shfl_xor(ai.z, 32, 64);
        bi4.w = __shfl_xor(ai.w, 32, 64);
        acc += __builtin_bit_cast(h8v, bi4);
    }
    if (half == 0) {
        *(h8v*)(Pz + ((size_t)q * CROWS + (size_t)n * 2) * HH + (size_t)li * 8) = acc;
    }
}

// ---------------- MFMA x NZ, IN-PLACE, chunk-routed (blockIdx&7 = q), coalesced stores ----
// B_z = B_z * W_z + bias_z, fused BN stats; 64-row tiles, LDS-staged output.
__global__ void __launch_bounds__(256) k_mfma3(_Float16* B0, _Float16* B1, _Float16* B2,
                                               const _Float16* __restrict__ Wh_g,
                                               const float* bias0, const float* bias1,
                                               const float* bias2,
                                               float* __restrict__ pS1,
                                               float* __restrict__ pS2) {
    __shared__ _Float16 st[64 * 128];           // 16 KB output staging
    __shared__ float rb1[4][128], rb2[4][128];  // 4 KB stats reduction
    int z = blockIdx.y;
    _Float16* B = (z == 0) ? B0 : ((z == 1) ? B1 : B2);
    const _Float16* Wh = Wh_g + (size_t)z * 16384;
    const float* bias = (z == 0) ? bias0 : ((z == 1) ? bias1 : bias2);
    int t = threadIdx.x;
    int w = t >> 6, l = t & 63;
    int rw = w >> 1, cw = w & 1;
    int lr = l & 31, hi = l >> 5;
    int q = blockIdx.x & 7;        // chunk -> XCD routing (matches gather's writer)
    int tile = blockIdx.x >> 3;    // 0..281
    int vrows = CROWS - tile * 64;
    if (vrows > 64) vrows = 64;
    size_t rbase = (size_t)q * CROWS + (size_t)tile * 64;
    const _Float16* Pr0 = B + (rbase + rw * 32 + lr) * HH;
    const _Float16* Wc0 = Wh + (size_t)(cw * 64 + lr) * HH;
    const _Float16* Wc1 = Wh + (size_t)(cw * 64 + 32 + lr) * HH;
    float16v acc2[2];
#pragma unroll
    for (int ct = 0; ct < 2; ct++) acc2[ct] = (float16v)(0.0f);
#pragma unroll
    for (int ks = 0; ks < 8; ks++) {
        int koff = ks * 16 + hi * 8;
        h8v a0 = *(const h8v*)(Pr0 + koff);
        h8v b0 = *(const h8v*)(Wc0 + koff);
        h8v b1 = *(const h8v*)(Wc1 + koff);
        acc2[0] = __builtin_amdgcn_mfma_f32_32x32x16_f16(a0, b0, acc2[0], 0, 0, 0);
        acc2[1] = __builtin_amdgcn_mfma_f32_32x32x16_f16(a0, b1, acc2[1], 0, 0, 0);
    }
    // epilogue: bias + stats into regs, f16 into LDS staging
    float bv[2] = {bias[cw * 64 + lr], bias[cw * 64 + 32 + lr]};
    float s1a[2] = {0.f, 0.f}, s2a[2] = {0.f, 0.f};
#pragma unroll
    for (int ct = 0; ct < 2; ct++) {
        int c = cw * 64 + ct * 32 + lr;
#pragma unroll
        for (int g = 0; g < 16; g++) {
            int row = rw * 32 + (g & 3) + 8 * (g >> 2) + 4 * hi;
            float v = acc2[ct][g] + bv[ct];
            if (row < vrows) {
                s1a[ct] += v;
                s2a[ct] += v * v;
            }
            st[row * 128 + c] = (_Float16)v;
        }
    }
    int slot = rw * 2 + hi;
#pragma unroll
    for (int ct = 0; ct < 2; ct++) {
        int cidx = cw * 64 + ct * 32 + lr;
        rb1[slot][cidx] = s1a[ct];
        rb2[slot][cidx] = s2a[ct];
    }
    __syncthreads();  // all K-loop reads done; staging complete
    // coalesced stores: thread t -> row t>>2, 32-ch segment t&3 (64 B/thread)
    {
        int row = t >> 2, seg = (t & 3) * 32;
        if (row < vrows) {
            const h8v* s = (const h8v*)(st + row * 128 + seg);
            h8v* dp = (h8v*)(B + (rbase + row) * HH + seg);
            dp[0] = s[0];
            dp[1] = s[1];
            dp[2] = s[2];
            dp[3] = s[3];
        }
    }
    if (t < 128) {
        float a1 = rb1[0][t] + rb1[1][t] + rb1[2][t] + rb1[3][t];
        float a2 = rb2[0][t] + rb2[1][t] + rb2[2][t] + rb2[3][t];
        pS1[((size_t)z * HH + t) * NT3 + blockIdx.x] = a1;
        pS2[((size_t)z * HH + t) * NT3 + blockIdx.x] = a2;
    }
}

// finalize BN affine from transposed partials, grid = NZ*128 blocks
__global__ void __launch_bounds__(256) k_bnfin3(const float* __restrict__ pS1,
                                                const float* __restrict__ pS2, int npart,
                                                const float* g0, const float* g1,
                                                const float* g2, const float* be0,
                                                const float* be1, const float* be2,
                                                float* __restrict__ scale,
                                                float* __restrict__ shiftv) {
    __shared__ float R1[256], R2[256];
    int z = blockIdx.x >> 7, c = blockIdx.x & 127;
    const float* g = (z == 0) ? g0 : ((z == 1) ? g1 : g2);
    const float* be = (z == 0) ? be0 : ((z == 1) ? be1 : be2);
    int t = threadIdx.x;
    const float* p1 = pS1 + ((size_t)z * HH + c) * npart;
    const float* p2 = pS2 + ((size_t)z * HH + c) * npart;
    float s1 = 0.f, s2 = 0.f;
    for (int i = t; i < npart; i += 256) {
        s1 += p1[i];
        s2 += p2[i];
    }
    R1[t] = s1;
    R2[t] = s2;
    __syncthreads();
    for (int d = 128; d > 0; d >>= 1) {
        if (t < d) {
            R1[t] += R1[t + d];
            R2[t] += R2[t + d];
        }
        __syncthreads();
    }
    if (t == 0) {
        float inv = 1.0f / (float)RR;
        float mu = R1[0] * inv;
        float var = R2[0] * inv - mu * mu;
        float sc = g[c] * rsqrtf(var + EPSB);
        scale[z * HH + c] = sc;
        shiftv[z * HH + c] = be[c] - mu * sc;
    }
}

// fused BN-affine + ReLU + mean-pool, chunk-routed: blockIdx.x = (nt*2+par)*8 + q
__global__ void __launch_bounds__(256) k_pool3(const _Float16* B0, const _Float16* B1,
                                               const _Float16* B2,
                                               const float* __restrict__ scale,
                                               const float* __restrict__ shiftv,
                                               float* __restrict__ pooled) {
    __shared__ float L[256][8];
    int z = blockIdx.y;
    const _Float16* A = (z == 0) ? B0 : ((z == 1) ? B1 : B2);
    const float* sc0 = scale + z * HH;
    const float* sh0 = shiftv + z * HH;
    float* pz = pooled + (size_t)z * BB * HH;
    int t = threadIdx.x;
    int q = blockIdx.x & 7;
    int rr = blockIdx.x >> 3;   // 0..71
    int par = rr & 1;
    int n0 = (rr >> 1) * 250;   // 36 tiles x 250 nodes
    int b = q * 2 + par;
    int ng = t >> 4, c8 = (t & 15) * 8;
    float sc[8], sh[8];
#pragma unroll
    for (int j = 0; j < 8; j++) {
        sc[j] = sc0[c8 + j];
        sh[j] = sh0[c8 + j];
    }
    const _Float16* Ab = A + ((size_t)q * CROWS + par) * HH;
    float acc[8];
#pragma unroll
    for (int j = 0; j < 8; j++) acc[j] = 0.f;
    for (int n = n0 + ng; n < n0 + 250; n += 16) {
        h8v v = *(const h8v*)(Ab + (size_t)n * 2 * HH + c8);
#pragma unroll
        for (int j = 0; j < 8; j++) {
            float f = (float)v[j] * sc[j] + sh[j];
            acc[j] += fmaxf(f, 0.f);
        }
    }
#pragma unroll
    for (int j = 0; j < 8; j++) L[t][j] = acc[j];
    __syncthreads();
    if (ng == 0) {
#pragma unroll
        for (int g = 1; g < 16; g++)
#pragma unroll
            for (int j = 0; j < 8; j++) acc[j] += L[t + 16 * g][j];
#pragma unroll
        for (int j = 0; j < 8; j++) atomicAdd(&pz[b * HH + t * 8 + j], acc[j]);
    }
}

// all 9 heads: linear + log_softmax
__global__ void __launch_bounds__(192) k_head_all(const float* __restrict__ pooled,
                                                  const float* __restrict__ main_Wf,
                                                  const float* __restrict__ main_bf,
                                                  const float* __restrict__ aux_Wf,
                                                  const float* __restrict__ aux_bf,
                                                  float* __restrict__ out) {
    int hd = blockIdx.x;
    const float* Wf = hd ? aux_Wf + (size_t)(hd - 1) * HH * NCLSS : main_Wf;
    const float* bf = hd ? aux_bf + (hd - 1) * NCLSS : main_bf;
    const float* pl = pooled + (size_t)hd * BB * HH;
    __shared__ float z[BB][NCLSS];
    __shared__ float lse[BB];
    int t = threadIdx.x;
    int b = t / NCLSS, j = t % NCLSS;
    if (t < BB * NCLSS) {
        float acc = bf[j];
        const float invn = 1.0f / NN;
        for (int c = 0; c < HH; c++) acc += pl[b * HH + c] * invn * Wf[c * NCLSS + j];
        z[b][j] = acc;
    }
    __syncthreads();
    if (t < BB) {
        float m = -1e30f;
        for (int j2 = 0; j2 < NCLSS; j2++) m = fmaxf(m, z[t][j2]);
        float s = 0.f;
        for (int j2 = 0; j2 < NCLSS; j2++) s += expf(z[t][j2] - m);
        lse[t] = m + logf(s);
    }
    __syncthreads();
    if (t < BB * NCLSS) {
        float* o = hd ? out + BB * NCLSS + ((size_t)b * 8 + (hd - 1)) * NCLSS + j
                      : out + b * NCLSS + j;
        *o = z[b][j] - lse[b];
    }
}

// ---------------- host ----------------

extern "C" void kernel_launch(void* const* d_in, const int* in_sizes, int n_in, void* d_out,
                              int out_size, void* d_ws, size_t ws_size, hipStream_t stream) {
    const float* x = (const float*)d_in[0];
    const int* ei = (const int*)d_in[1];
    const float* W_in = (const float*)d_in[2];
    const float* b_in = (const float*)d_in[3];
    const float* g_in = (const float*)d_in[4];
    const float* be_in = (const float*)d_in[5];
    const float* shared_W = (const float*)d_in[6];
    const float* shared_b = (const float*)d_in[7];
    const float* shared_g = (const float*)d_in[8];
    const float* shared_be = (const float*)d_in[9];
    const float* main_Wg = (const float*)d_in[10];
    const float* main_bg = (const float*)d_in[11];
    const float* main_g = (const float*)d_in[12];
    const float* main_be = (const float*)d_in[13];
    const float* main_Wf = (const float*)d_in[14];
    const float* main_bf = (const float*)d_in[15];
    const float* aux_Wg = (const float*)d_in[16];
    const float* aux_bg = (const float*)d_in[17];
    const float* aux_g = (const float*)d_in[18];
    const float* aux_be = (const float*)d_in[19];
    const float* aux_Wf = (const float*)d_in[20];
    const float* aux_bf = (const float*)d_in[21];
    float* out = (float*)d_out;

    char* w = (char*)d_ws;
    const size_t BIG = (size_t)RR * HH * 2;
    _Float16* U = (_Float16*)w;  w += BIG;
    _Float16* V = (_Float16*)w;  w += BIG;
    _Float16* P = (_Float16*)w;  w += BIG;
    _Float16* HP = (_Float16*)w; w += BIG;
    float* P0 = (float*)w;       w += (size_t)RR * 2 * 4;
    _Float16* Wh = (_Float16*)w; w += (size_t)11 * 16384 * 2;
    int2* csr = (int2*)w;        w += (size_t)102400 * 8;
    int* counts = (int*)w;       w += NN * 4;
    int* cursor = (int*)w;       w += NN * 4;
    float* dinv = (float*)w;     w += NN * 4;
    unsigned* d2p = (unsigned*)w; w += NN * 4;
    int* rowptr4 = (int*)w;      w += 36016;
    float* pS1 = (float*)w;      w += (size_t)3 * HH * NT3 * 4;
    float* pS2 = (float*)w;      w += (size_t)3 * HH * NT3 * 4;
    float* pooled = (float*)w;   w += 9 * BB * HH * 4;
    float* tscale = (float*)w;   w += 512;
    float* tshift = (float*)w;   w += 512;
    float* hscale = (float*)w;   w += 2048;
    float* hshift = (float*)w;   w += 2048;

    hipMemsetAsync(counts, 0, 2 * NN * 4, stream);
    hipMemsetAsync(pooled, 0, 9 * BB * HH * 4, stream);

    k_count<<<(EE + 255) / 256, 256, 0, stream>>>(ei, counts);
    k_dinv<<<(NN + 255) / 256, 256, 0, stream>>>(counts, dinv, d2p);
    k_scan<<<1, 1024, 0, stream>>>(counts, rowptr4);
    k_fill<<<(EE + 255) / 256, 256, 0, stream>>>(ei, rowptr4, cursor, dinv, csr);
    k_pad<<<(NN + 255) / 256, 256, 0, stream>>>(rowptr4, cursor, csr);
    k_wcvt<<<(11 * 16384 + 255) / 256, 256, 0, stream>>>(shared_W, main_Wg, aux_Wg, Wh);

    // L0: prop x, K=2 matmul -> U (pre-BN), stats -> tscale/tshift
    {
        dim3 g((NN + 255) / 256, BB);
        k_prop2<<<g, 256, 0, stream>>>(x, P0, rowptr4, csr, dinv);
        k_mm2<<<NPART0, 256, 0, stream>>>(P0, U, W_in, b_in, pS1, pS2);
        k_bnfin3<<<HH, 256, 0, stream>>>(pS1, pS2, NPART0, g_in, g_in, g_in, be_in, be_in,
                                         be_in, tscale, tshift);
    }

    // trunk layer 0: act(U->HP), gather(HP->V), mfma in-place (V), bnfin
    k_act<<<RR * 16 / 256, 256, 0, stream>>>(U, HP, tscale, tshift);
    k_gather3<<<dim3(8 * 2250, 1), 256, 0, stream>>>(HP, V, V, V, rowptr4, csr, d2p, 0);
    k_mfma3<<<dim3(NT3, 1), 256, 0, stream>>>(V, V, V, Wh, shared_b, shared_b, shared_b,
                                              pS1, pS2);
    k_bnfin3<<<HH, 256, 0, stream>>>(pS1, pS2, NT3, shared_g, shared_g, shared_g, shared_be,
                                     shared_be, shared_be, tscale, tshift);
    // trunk layer 1: act(V->HP), gather(HP->U), mfma in-place (U), bnfin
    k_act<<<RR * 16 / 256, 256, 0, stream>>>(V, HP, tscale, tshift);
    k_gather3<<<dim3(8 * 2250, 1), 256, 0, stream>>>(HP, U, U, U, rowptr4, csr, d2p, 0);
    k_mfma3<<<dim3(NT3, 1), 256, 0, stream>>>(U, U, U, Wh + 16384, shared_b + HH,
                                              shared_b + HH, shared_b + HH, pS1, pS2);
    k_bnfin3<<<HH, 256, 0, stream>>>(pS1, pS2, NT3, shared_g + HH, shared_g + HH,
                                     shared_g + HH, shared_be + HH, shared_be + HH,
                                     shared_be + HH, tscale, tshift);
    // trunk output activation (shared by all 9 heads)
    k_act<<<RR * 16 / 256, 256, 0, stream>>>(U, HP, tscale, tshift);

    // heads in 3 groups of 3: {P,U,V} hold the 3 propagations, processed in-place
    for (int g = 0; g < 3; g++) {
        int h0 = g * 3;
        const float* bg[3];
        const float* gg[3];
        const float* be[3];
        for (int z = 0; z < 3; z++) {
            int hd = h0 + z;
            bg[z] = (hd == 0) ? main_bg : aux_bg + (hd - 1) * HH;
            gg[z] = (hd == 0) ? main_g : aux_g + (hd - 1) * HH;
            be[z] = (hd == 0) ? main_be : aux_be + (hd - 1) * HH;
        }
        k_gather3<<<dim3(8 * 2250, 3), 256, 0, stream>>>(HP, P, U, V, rowptr4, csr, d2p,
                                                         h0 * 1000);
        k_mfma3<<<dim3(NT3, 3), 256, 0, stream>>>(P, U, V, Wh + (size_t)(2 + h0) * 16384,
                                                  bg[0], bg[1], bg[2], pS1, pS2);
        k_bnfin3<<<3 * HH, 256, 0, stream>>>(pS1, pS2, NT3, gg[0], gg[1], gg[2], be[0],
                                             be[1], be[2], hscale, hshift);
        k_pool3<<<dim3(576, 3), 256, 0, stream>>>(P, U, V, hscale, hshift,
                                                  pooled + (size_t)h0 * BB * HH);
    }
    k_head_all<<<9, 192, 0, stream>>>(pooled, main_Wf, main_bf, aux_Wf, aux_bf, out);
}

// Round 19
// 780.613 us; speedup vs baseline: 1.3782x; 1.1921x over previous
//
#include <hip/hip_runtime.h>
#include <hip/hip_bf16.h>
#include <math.h>

#define BB 16
#define TT 360
#define VV 25
#define NN 9000
#define EE 72000
#define HH 128
#define RR (NN * BB)      // 144000 rows total
#define CROWS 18000       // rows per chunk (9000 nodes x 2 batches)
#define NT128 1125        // 128-row tiles (exact)
#define NPART0 563        // partial-stats blocks for k_mm2 (L0)
#define NCLSS 12
#define EPSB 1e-5f

// chunked activation layout: row R(n,b) = (b>>1)*CROWS + n*2 + (b&1)

typedef _Float16 h8v __attribute__((ext_vector_type(8)));
typedef float float16v __attribute__((ext_vector_type(16)));

__device__ __forceinline__ h8v cf8(unsigned packed) {
    uint4 cc = {packed, packed, packed, packed};
    return __builtin_bit_cast(h8v, cc);
}

// ---------------- graph preprocessing ----------------

__global__ void k_count(const int* __restrict__ ei, int* __restrict__ counts) {
    int e = blockIdx.x * 256 + threadIdx.x;
    if (e < EE) atomicAdd(&counts[ei[EE + e]], 1);
}

__global__ void k_dinv(const int* __restrict__ counts, float* __restrict__ dinv,
                       unsigned* __restrict__ d2p) {
    int n = blockIdx.x * 256 + threadIdx.x;
    if (n >= NN) return;
    float di = rsqrtf((float)(counts[n] + 1));
    dinv[n] = di;
    _Float16 d2 = (_Float16)(di * di);
    unsigned short u = __builtin_bit_cast(unsigned short, d2);
    d2p[n] = (unsigned)u | ((unsigned)u << 16);
}

__global__ void k_scan(const int* __restrict__ counts, int* __restrict__ rowptr4) {
    __shared__ int part[1024];
    int t = threadIdx.x;
    int base = t * 9;
    int loc[9];
    int s = 0;
#pragma unroll
    for (int i = 0; i < 9; i++) {
        int idx = base + i;
        int v = (idx < NN) ? ((counts[idx] + 3) & ~3) : 0;
        loc[i] = s;
        s += v;
    }
    part[t] = s;
    __syncthreads();
    for (int d = 1; d < 1024; d <<= 1) {
        int v = (t >= d) ? part[t - d] : 0;
        __syncthreads();
        part[t] += v;
        __syncthreads();
    }
    int excl = (t == 0) ? 0 : part[t - 1];
#pragma unroll
    for (int i = 0; i < 9; i++) {
        int idx = base + i;
        if (idx < NN) rowptr4[idx] = excl + loc[i];
    }
    if (t == 1023) rowptr4[NN] = part[1023];
}

__global__ void k_fill(const int* __restrict__ ei, const int* __restrict__ rowptr4,
                       int* __restrict__ cursor, const float* __restrict__ dinv,
                       int2* __restrict__ csr) {
    int e = blockIdx.x * 256 + threadIdx.x;
    if (e >= EE) return;
    int s = ei[e], d = ei[EE + e];
    int slot = rowptr4[d] + atomicAdd(&cursor[d], 1);
    _Float16 cfh = (_Float16)(dinv[s] * dinv[d]);
    unsigned short u = __builtin_bit_cast(unsigned short, cfh);
    int2 e2;
    e2.x = s;
    e2.y = (int)((unsigned)u | ((unsigned)u << 16));
    csr[slot] = e2;
}

__global__ void k_pad(const int* __restrict__ rowptr4, const int* __restrict__ cursor,
                      int2* __restrict__ csr) {
    int n = blockIdx.x * 256 + threadIdx.x;
    if (n >= NN) return;
    int beg = rowptr4[n] + cursor[n];
    int end = rowptr4[n + 1];
    int2 z;
    z.x = n;
    z.y = 0;
    for (int e = beg; e < end; e++) csr[e] = z;
}

// pre-convert the 11 layer weight matrices to f16 W^T images: Wh[l][c*128+k]
__global__ void k_wcvt(const float* __restrict__ sW, const float* __restrict__ mW,
                       const float* __restrict__ aW, _Float16* __restrict__ Wh) {
    int idx = blockIdx.x * 256 + threadIdx.x;
    if (idx >= 11 * 16384) return;
    int l = idx >> 14, r = idx & 16383;
    int k = r >> 7, c = r & 127;
    const float* src = (l < 2) ? sW + (size_t)l * 16384
                               : ((l == 2) ? mW : aW + (size_t)(l - 3) * 16384);
    Wh[(size_t)l * 16384 + c * 128 + k] = (_Float16)src[k * 128 + c];
}

// ---------------- L0 propagation of raw x (2 channels, f32) ----------------
__global__ void k_prop2(const float* __restrict__ x, float* __restrict__ P0,
                        const int* __restrict__ rowptr4, const int2* __restrict__ csr,
                        const float* __restrict__ dinv) {
    int n = blockIdx.x * 256 + threadIdx.x;
    if (n >= NN) return;
    int b = blockIdx.y;
    const float* xb = x + (size_t)b * NN * 2;
    float d2 = dinv[n] * dinv[n];
    float a0 = d2 * xb[2 * n], a1 = d2 * xb[2 * n + 1];
    int beg = rowptr4[n], end = rowptr4[n + 1];
    for (int j = beg; j < end; j++) {
        int2 e2 = csr[j];
        int s = e2.x;
        unsigned short u = (unsigned short)((unsigned)e2.y & 0xffffu);
        float cf = (float)__builtin_bit_cast(_Float16, u);
        a0 += cf * xb[2 * s];
        a1 += cf * xb[2 * s + 1];
    }
    float* Pb = P0 + (size_t)(n * BB + b) * 2;
    Pb[0] = a0;
    Pb[1] = a1;
}

// L0 matmul (K=2), writes chunked f16 layout, fused BN partial stats pS[c][part].
__global__ void __launch_bounds__(256) k_mm2(const float* __restrict__ P0,
                                             _Float16* __restrict__ A,
                                             const float* __restrict__ W,
                                             const float* __restrict__ bias,
                                             float* __restrict__ pS1, float* __restrict__ pS2) {
    __shared__ float L1[256][8], L2[256][8];
    int t = threadIdx.x;
    int cg = t & 15, c8 = cg * 8;
    float wv0[8], wv1[8], bv[8];
#pragma unroll
    for (int j = 0; j < 8; j++) {
        wv0[j] = W[c8 + j];
        wv1[j] = W[HH + c8 + j];
        bv[j] = bias[c8 + j];
    }
    float s1[8], s2[8];
#pragma unroll
    for (int j = 0; j < 8; j++) { s1[j] = 0.f; s2[j] = 0.f; }
    for (int idx = blockIdx.x * 256 + t; idx < RR * 16; idx += gridDim.x * 256) {
        int Rr = idx >> 4;
        int q = Rr / CROWS;
        int rr = Rr - q * CROWS;
        int n = rr >> 1;
        int b = q * 2 + (rr & 1);
        float p0 = P0[((size_t)n * BB + b) * 2], p1 = P0[((size_t)n * BB + b) * 2 + 1];
        h8v o;
#pragma unroll
        for (int j = 0; j < 8; j++) {
            float v = p0 * wv0[j] + p1 * wv1[j] + bv[j];
            s1[j] += v;
            s2[j] += v * v;
            o[j] = (_Float16)v;
        }
        *(h8v*)(A + (size_t)Rr * HH + c8) = o;
    }
#pragma unroll
    for (int j = 0; j < 8; j++) { L1[t][j] = s1[j]; L2[t][j] = s2[j]; }
    __syncthreads();
    if (t < 16) {
#pragma unroll
        for (int g = 1; g < 16; g++)
#pragma unroll
            for (int j = 0; j < 8; j++) {
                s1[j] = (g == 1 ? L1[t][j] : s1[j]) + L1[t + 16 * g][j];
                s2[j] = (g == 1 ? L2[t][j] : s2[j]) + L2[t + 16 * g][j];
            }
#pragma unroll
        for (int j = 0; j < 8; j++) {
            pS1[(size_t)(t * 8 + j) * NPART0 + blockIdx.x] = s1[j];
            pS2[(size_t)(t * 8 + j) * NPART0 + blockIdx.x] = s2[j];
        }
    }
}

// ---------------- activation pass: h' = relu(A*sc+sh), f16 -> f16 ----------------
__global__ void __launch_bounds__(256) k_act(const _Float16* __restrict__ A,
                                             _Float16* __restrict__ HP,
                                             const float* __restrict__ scale,
                                             const float* __restrict__ shiftv) {
    int i = blockIdx.x * 256 + threadIdx.x;
    int c8 = (i & 15) * 8;
    h8v v = *(const h8v*)(A + (size_t)i * 8);
    h8v o;
#pragma unroll
    for (int j = 0; j < 8; j++) {
        float f = (float)v[j] * scale[c8 + j] + shiftv[c8 + j];
        o[j] = (_Float16)fmaxf(f, 0.f);
    }
    *(h8v*)(HP + (size_t)i * 8) = o;
}

// ---------------- gather x NZ: P_z = A_hat * shift_z(h') (round-13 proven body) ----
__global__ void __launch_bounds__(256) k_gather3(const _Float16* __restrict__ h,
                                                 _Float16* B0, _Float16* B1, _Float16* B2,
                                                 const int* __restrict__ rowptr4,
                                                 const int2* __restrict__ csr,
                                                 const unsigned* __restrict__ d2p, int shbase) {
    int z = blockIdx.y;
    _Float16* Pz = (z == 0) ? B0 : ((z == 1) ? B1 : B2);
    int shn = shbase + z * 1000;
    int t = threadIdx.x;
    int q = blockIdx.x & 7;
    int ng4 = blockIdx.x >> 3;
    int wv = t >> 6, l = t & 63;
    int n = ng4 * 4 + wv;
    int half = l >> 5, li = l & 31;
    const _Float16* hb = h + (size_t)q * CROWS * HH + (size_t)li * 8;
    int pn = n + shn;
    if (pn >= NN) pn -= NN;
    h8v acc;
    {
        h8v v = *(const h8v*)(hb + (size_t)pn * 2 * HH);
        acc = v * cf8(half ? 0u : d2p[n]);
    }
    int beg = rowptr4[n], end = rowptr4[n + 1];
    int e = beg;
    for (; e + 8 <= end; e += 8) {
        int4 m0 = *(const int4*)(csr + e);
        int4 m1 = *(const int4*)(csr + e + 2);
        int4 m2 = *(const int4*)(csr + e + 4);
        int4 m3 = *(const int4*)(csr + e + 6);
        int s0 = (half ? m0.z : m0.x) + shn; if (s0 >= NN) s0 -= NN;
        int s1 = (half ? m1.z : m1.x) + shn; if (s1 >= NN) s1 -= NN;
        int s2 = (half ? m2.z : m2.x) + shn; if (s2 >= NN) s2 -= NN;
        int s3 = (half ? m3.z : m3.x) + shn; if (s3 >= NN) s3 -= NN;
        h8v v0 = *(const h8v*)(hb + (size_t)s0 * 2 * HH);
        h8v v1 = *(const h8v*)(hb + (size_t)s1 * 2 * HH);
        h8v v2 = *(const h8v*)(hb + (size_t)s2 * 2 * HH);
        h8v v3 = *(const h8v*)(hb + (size_t)s3 * 2 * HH);
        acc += v0 * cf8((unsigned)(half ? m0.w : m0.y));
        acc += v1 * cf8((unsigned)(half ? m1.w : m1.y));
        acc += v2 * cf8((unsigned)(half ? m2.w : m2.y));
        acc += v3 * cf8((unsigned)(half ? m3.w : m3.y));
    }
    if (e < end) {
        int4 m0 = *(const int4*)(csr + e);
        int4 m1 = *(const int4*)(csr + e + 2);
        int s0 = (half ? m0.z : m0.x) + shn; if (s0 >= NN) s0 -= NN;
        int s1 = (half ? m1.z : m1.x) + shn; if (s1 >= NN) s1 -= NN;
        h8v v0 = *(const h8v*)(hb + (size_t)s0 * 2 * HH);
        h8v v1 = *(const h8v*)(hb + (size_t)s1 * 2 * HH);
        acc += v0 * cf8((unsigned)(half ? m0.w : m0.y));
        acc += v1 * cf8((unsigned)(half ? m1.w : m1.y));
    }
    {
        int4 ai = __builtin_bit_cast(int4, acc);
        int4 bi4;
        bi4.x = __shfl_xor(ai.x, 32, 64);
        bi4.y = __shfl_xor(ai.y, 32, 64);
        bi4.z = __shfl_xor(ai.z, 32, 64);
        bi4.w = __shfl_xor(ai.w, 32, 64);
        acc += __builtin_bit_cast(h8v, bi4);
    }
    if (half == 0) {
        *(h8v*)(Pz + ((size_t)q * CROWS + (size_t)n * 2) * HH + (size_t)li * 8) = acc;
    }
}

// ---------------- MFMA x NZ, IN-PLACE, 128-row blocks (dual 64-row tiles, shared W) ----
// B_z = B_z * W_z + bias_z, fused BN stats. 2 independent MFMA chains per thread.
__global__ void __launch_bounds__(256) k_mfma3(_Float16* B0, _Float16* B1, _Float16* B2,
                                               const _Float16* __restrict__ Wh_g,
                                               const float* bias0, const float* bias1,
                                               const float* bias2,
                                               float* __restrict__ pS1,
                                               float* __restrict__ pS2) {
    __shared__ float rb1[4][128], rb2[4][128];  // 4 KB stats reduction
    int z = blockIdx.y;
    _Float16* B = (z == 0) ? B0 : ((z == 1) ? B1 : B2);
    const _Float16* Wh = Wh_g + (size_t)z * 16384;
    const float* bias = (z == 0) ? bias0 : ((z == 1) ? bias1 : bias2);
    int t = threadIdx.x;
    int w = t >> 6, l = t & 63;
    int rw = w >> 1, cw = w & 1;  // 32-row half (within each tile) x 64-col half
    int lr = l & 31, hi = l >> 5;
    size_t rbase = (size_t)blockIdx.x * 128;
    const _Float16* Pr0 = B + (rbase + rw * 32 + lr) * HH;        // tile 0
    const _Float16* Pr1 = B + (rbase + 64 + rw * 32 + lr) * HH;   // tile 1
    const _Float16* Wc0 = Wh + (size_t)(cw * 64 + lr) * HH;
    const _Float16* Wc1 = Wh + (size_t)(cw * 64 + 32 + lr) * HH;
    float16v acc2[2][2];  // [tile][col-sub]
#pragma unroll
    for (int rt = 0; rt < 2; rt++)
#pragma unroll
        for (int ct = 0; ct < 2; ct++) acc2[rt][ct] = (float16v)(0.0f);
#pragma unroll
    for (int ks = 0; ks < 8; ks++) {
        int koff = ks * 16 + hi * 8;
        h8v a0 = *(const h8v*)(Pr0 + koff);
        h8v a1 = *(const h8v*)(Pr1 + koff);
        h8v b0 = *(const h8v*)(Wc0 + koff);
        h8v b1 = *(const h8v*)(Wc1 + koff);
        acc2[0][0] = __builtin_amdgcn_mfma_f32_32x32x16_f16(a0, b0, acc2[0][0], 0, 0, 0);
        acc2[0][1] = __builtin_amdgcn_mfma_f32_32x32x16_f16(a0, b1, acc2[0][1], 0, 0, 0);
        acc2[1][0] = __builtin_amdgcn_mfma_f32_32x32x16_f16(a1, b0, acc2[1][0], 0, 0, 0);
        acc2[1][1] = __builtin_amdgcn_mfma_f32_32x32x16_f16(a1, b1, acc2[1][1], 0, 0, 0);
    }
    __syncthreads();  // drain all waves' reads of this 128-row block before overwrite
    // epilogue: bias, stats, in-place f16 stores
    float bv[2] = {bias[cw * 64 + lr], bias[cw * 64 + 32 + lr]};
    float s1a[2] = {0.f, 0.f}, s2a[2] = {0.f, 0.f};
#pragma unroll
    for (int rt = 0; rt < 2; rt++)
#pragma unroll
        for (int ct = 0; ct < 2; ct++) {
            int c = cw * 64 + ct * 32 + lr;
#pragma unroll
            for (int g = 0; g < 16; g++) {
                int row = rt * 64 + rw * 32 + (g & 3) + 8 * (g >> 2) + 4 * hi;
                float v = acc2[rt][ct][g] + bv[ct];
                s1a[ct] += v;
                s2a[ct] += v * v;
                B[(rbase + row) * HH + c] = (_Float16)v;
            }
        }
    int slot = rw * 2 + hi;
#pragma unroll
    for (int ct = 0; ct < 2; ct++) {
        int cidx = cw * 64 + ct * 32 + lr;
        rb1[slot][cidx] = s1a[ct];
        rb2[slot][cidx] = s2a[ct];
    }
    __syncthreads();
    if (t < 128) {
        float a1 = rb1[0][t] + rb1[1][t] + rb1[2][t] + rb1[3][t];
        float a2 = rb2[0][t] + rb2[1][t] + rb2[2][t] + rb2[3][t];
        pS1[((size_t)z * HH + t) * NT128 + blockIdx.x] = a1;
        pS2[((size_t)z * HH + t) * NT128 + blockIdx.x] = a2;
    }
}

// finalize BN affine from transposed partials, grid = NZ*128 blocks
__global__ void __launch_bounds__(256) k_bnfin3(const float* __restrict__ pS1,
                                                const float* __restrict__ pS2, int npart,
                                                const float* g0, const float* g1,
                                                const float* g2, const float* be0,
                                                const float* be1, const float* be2,
                                                float* __restrict__ scale,
                                                float* __restrict__ shiftv) {
    __shared__ float R1[256], R2[256];
    int z = blockIdx.x >> 7, c = blockIdx.x & 127;
    const float* g = (z == 0) ? g0 : ((z == 1) ? g1 : g2);
    const float* be = (z == 0) ? be0 : ((z == 1) ? be1 : be2);
    int t = threadIdx.x;
    const float* p1 = pS1 + ((size_t)z * HH + c) * npart;
    const float* p2 = pS2 + ((size_t)z * HH + c) * npart;
    float s1 = 0.f, s2 = 0.f;
    for (int i = t; i < npart; i += 256) {
        s1 += p1[i];
        s2 += p2[i];
    }
    R1[t] = s1;
    R2[t] = s2;
    __syncthreads();
    for (int d = 128; d > 0; d >>= 1) {
        if (t < d) {
            R1[t] += R1[t + d];
            R2[t] += R2[t + d];
        }
        __syncthreads();
    }
    if (t == 0) {
        float inv = 1.0f / (float)RR;
        float mu = R1[0] * inv;
        float var = R2[0] * inv - mu * mu;
        float sc = g[c] * rsqrtf(var + EPSB);
        scale[z * HH + c] = sc;
        shiftv[z * HH + c] = be[c] - mu * sc;
    }
}

// fused BN-affine + ReLU + mean-pool x3 heads: grid (36, BB, 3)
__global__ void __launch_bounds__(256) k_pool3(const _Float16* B0, const _Float16* B1,
                                               const _Float16* B2,
                                               const float* __restrict__ scale,
                                               const float* __restrict__ shiftv,
                                               float* __restrict__ pooled) {
    __shared__ float L[256][8];
    int z = blockIdx.z;
    const _Float16* A = (z == 0) ? B0 : ((z == 1) ? B1 : B2);
    const float* sc0 = scale + z * HH;
    const float* sh0 = shiftv + z * HH;
    float* pz = pooled + (size_t)z * BB * HH;
    int t = threadIdx.x;
    int b = blockIdx.y;
    int n0 = blockIdx.x * 250;
    int ng = t >> 4, c8 = (t & 15) * 8;
    float sc[8], sh[8];
#pragma unroll
    for (int j = 0; j < 8; j++) {
        sc[j] = sc0[c8 + j];
        sh[j] = sh0[c8 + j];
    }
    const _Float16* Ab = A + ((size_t)(b >> 1) * CROWS + (b & 1)) * HH;
    float acc[8];
#pragma unroll
    for (int j = 0; j < 8; j++) acc[j] = 0.f;
    for (int n = n0 + ng; n < n0 + 250; n += 16) {
        h8v v = *(const h8v*)(Ab + (size_t)n * 2 * HH + c8);
#pragma unroll
        for (int j = 0; j < 8; j++) {
            float f = (float)v[j] * sc[j] + sh[j];
            acc[j] += fmaxf(f, 0.f);
        }
    }
#pragma unroll
    for (int j = 0; j < 8; j++) L[t][j] = acc[j];
    __syncthreads();
    if (ng == 0) {
#pragma unroll
        for (int g = 1; g < 16; g++)
#pragma unroll
            for (int j = 0; j < 8; j++) acc[j] += L[t + 16 * g][j];
#pragma unroll
        for (int j = 0; j < 8; j++) atomicAdd(&pz[b * HH + t * 8 + j], acc[j]);
    }
}

// all 9 heads: linear + log_softmax
__global__ void __launch_bounds__(192) k_head_all(const float* __restrict__ pooled,
                                                  const float* __restrict__ main_Wf,
                                                  const float* __restrict__ main_bf,
                                                  const float* __restrict__ aux_Wf,
                                                  const float* __restrict__ aux_bf,
                                                  float* __restrict__ out) {
    int hd = blockIdx.x;
    const float* Wf = hd ? aux_Wf + (size_t)(hd - 1) * HH * NCLSS : main_Wf;
    const float* bf = hd ? aux_bf + (hd - 1) * NCLSS : main_bf;
    const float* pl = pooled + (size_t)hd * BB * HH;
    __shared__ float z[BB][NCLSS];
    __shared__ float lse[BB];
    int t = threadIdx.x;
    int b = t / NCLSS, j = t % NCLSS;
    if (t < BB * NCLSS) {
        float acc = bf[j];
        const float invn = 1.0f / NN;
        for (int c = 0; c < HH; c++) acc += pl[b * HH + c] * invn * Wf[c * NCLSS + j];
        z[b][j] = acc;
    }
    __syncthreads();
    if (t < BB) {
        float m = -1e30f;
        for (int j2 = 0; j2 < NCLSS; j2++) m = fmaxf(m, z[t][j2]);
        float s = 0.f;
        for (int j2 = 0; j2 < NCLSS; j2++) s += expf(z[t][j2] - m);
        lse[t] = m + logf(s);
    }
    __syncthreads();
    if (t < BB * NCLSS) {
        float* o = hd ? out + BB * NCLSS + ((size_t)b * 8 + (hd - 1)) * NCLSS + j
                      : out + b * NCLSS + j;
        *o = z[b][j] - lse[b];
    }
}

// ---------------- host ----------------

extern "C" void kernel_launch(void* const* d_in, const int* in_sizes, int n_in, void* d_out,
                              int out_size, void* d_ws, size_t ws_size, hipStream_t stream) {
    const float* x = (const float*)d_in[0];
    const int* ei = (const int*)d_in[1];
    const float* W_in = (const float*)d_in[2];
    const float* b_in = (const float*)d_in[3];
    const float* g_in = (const float*)d_in[4];
    const float* be_in = (const float*)d_in[5];
    const float* shared_W = (const float*)d_in[6];
    const float* shared_b = (const float*)d_in[7];
    const float* shared_g = (const float*)d_in[8];
    const float* shared_be = (const float*)d_in[9];
    const float* main_Wg = (const float*)d_in[10];
    const float* main_bg = (const float*)d_in[11];
    const float* main_g = (const float*)d_in[12];
    const float* main_be = (const float*)d_in[13];
    const float* main_Wf = (const float*)d_in[14];
    const float* main_bf = (const float*)d_in[15];
    const float* aux_Wg = (const float*)d_in[16];
    const float* aux_bg = (const float*)d_in[17];
    const float* aux_g = (const float*)d_in[18];
    const float* aux_be = (const float*)d_in[19];
    const float* aux_Wf = (const float*)d_in[20];
    const float* aux_bf = (const float*)d_in[21];
    float* out = (float*)d_out;

    char* w = (char*)d_ws;
    const size_t BIG = (size_t)RR * HH * 2;
    _Float16* U = (_Float16*)w;  w += BIG;
    _Float16* V = (_Float16*)w;  w += BIG;
    _Float16* P = (_Float16*)w;  w += BIG;
    _Float16* HP = (_Float16*)w; w += BIG;
    float* P0 = (float*)w;       w += (size_t)RR * 2 * 4;
    _Float16* Wh = (_Float16*)w; w += (size_t)11 * 16384 * 2;
    int2* csr = (int2*)w;        w += (size_t)102400 * 8;
    int* counts = (int*)w;       w += NN * 4;
    int* cursor = (int*)w;       w += NN * 4;
    float* dinv = (float*)w;     w += NN * 4;
    unsigned* d2p = (unsigned*)w; w += NN * 4;
    int* rowptr4 = (int*)w;      w += 36016;
    float* pS1 = (float*)w;      w += (size_t)3 * HH * NT128 * 4;
    float* pS2 = (float*)w;      w += (size_t)3 * HH * NT128 * 4;
    float* pooled = (float*)w;   w += 9 * BB * HH * 4;
    float* tscale = (float*)w;   w += 512;
    float* tshift = (float*)w;   w += 512;
    float* hscale = (float*)w;   w += 2048;
    float* hshift = (float*)w;   w += 2048;

    hipMemsetAsync(counts, 0, 2 * NN * 4, stream);
    hipMemsetAsync(pooled, 0, 9 * BB * HH * 4, stream);

    k_count<<<(EE + 255) / 256, 256, 0, stream>>>(ei, counts);
    k_dinv<<<(NN + 255) / 256, 256, 0, stream>>>(counts, dinv, d2p);
    k_scan<<<1, 1024, 0, stream>>>(counts, rowptr4);
    k_fill<<<(EE + 255) / 256, 256, 0, stream>>>(ei, rowptr4, cursor, dinv, csr);
    k_pad<<<(NN + 255) / 256, 256, 0, stream>>>(rowptr4, cursor, csr);
    k_wcvt<<<(11 * 16384 + 255) / 256, 256, 0, stream>>>(shared_W, main_Wg, aux_Wg, Wh);

    // L0: prop x, K=2 matmul -> U (pre-BN), stats -> tscale/tshift
    {
        dim3 g((NN + 255) / 256, BB);
        k_prop2<<<g, 256, 0, stream>>>(x, P0, rowptr4, csr, dinv);
        k_mm2<<<NPART0, 256, 0, stream>>>(P0, U, W_in, b_in, pS1, pS2);
        k_bnfin3<<<HH, 256, 0, stream>>>(pS1, pS2, NPART0, g_in, g_in, g_in, be_in, be_in,
                                         be_in, tscale, tshift);
    }

    // trunk layer 0: act(U->HP), gather(HP->V), mfma in-place (V), bnfin
    k_act<<<RR * 16 / 256, 256, 0, stream>>>(U, HP, tscale, tshift);
    k_gather3<<<dim3(8 * 2250, 1), 256, 0, stream>>>(HP, V, V, V, rowptr4, csr, d2p, 0);
    k_mfma3<<<dim3(NT128, 1), 256, 0, stream>>>(V, V, V, Wh, shared_b, shared_b, shared_b,
                                                pS1, pS2);
    k_bnfin3<<<HH, 256, 0, stream>>>(pS1, pS2, NT128, shared_g, shared_g, shared_g, shared_be,
                                     shared_be, shared_be, tscale, tshift);
    // trunk layer 1: act(V->HP), gather(HP->U), mfma in-place (U), bnfin
    k_act<<<RR * 16 / 256, 256, 0, stream>>>(V, HP, tscale, tshift);
    k_gather3<<<dim3(8 * 2250, 1), 256, 0, stream>>>(HP, U, U, U, rowptr4, csr, d2p, 0);
    k_mfma3<<<dim3(NT128, 1), 256, 0, stream>>>(U, U, U, Wh + 16384, shared_b + HH,
                                                shared_b + HH, shared_b + HH, pS1, pS2);
    k_bnfin3<<<HH, 256, 0, stream>>>(pS1, pS2, NT128, shared_g + HH, shared_g + HH,
                                     shared_g + HH, shared_be + HH, shared_be + HH,
                                     shared_be + HH, tscale, tshift);
    // trunk output activation (shared by all 9 heads)
    k_act<<<RR * 16 / 256, 256, 0, stream>>>(U, HP, tscale, tshift);

    // heads in 3 groups of 3: {P,U,V} hold the 3 propagations, processed in-place
    for (int g = 0; g < 3; g++) {
        int h0 = g * 3;
        const float* bg[3];
        const float* gg[3];
        const float* be[3];
        for (int z = 0; z < 3; z++) {
            int hd = h0 + z;
            bg[z] = (hd == 0) ? main_bg : aux_bg + (hd - 1) * HH;
            gg[z] = (hd == 0) ? main_g : aux_g + (hd - 1) * HH;
            be[z] = (hd == 0) ? main_be : aux_be + (hd - 1) * HH;
        }
        k_gather3<<<dim3(8 * 2250, 3), 256, 0, stream>>>(HP, P, U, V, rowptr4, csr, d2p,
                                                         h0 * 1000);
        k_mfma3<<<dim3(NT128, 3), 256, 0, stream>>>(P, U, V, Wh + (size_t)(2 + h0) * 16384,
                                                    bg[0], bg[1], bg[2], pS1, pS2);
        k_bnfin3<<<3 * HH, 256, 0, stream>>>(pS1, pS2, NT128, gg[0], gg[1], gg[2], be[0],
                                             be[1], be[2], hscale, hshift);
        k_pool3<<<dim3(36, BB, 3), 256, 0, stream>>>(P, U, V, hscale, hshift,
                                                     pooled + (size_t)h0 * BB * HH);
    }
    k_head_all<<<9, 192, 0, stream>>>(pooled, main_Wf, main_bf, aux_Wf, aux_bf, out);
}

// Round 20
// 734.921 us; speedup vs baseline: 1.4639x; 1.0622x over previous
//
#include <hip/hip_runtime.h>
#include <hip/hip_bf16.h>
#include <math.h>

#define BB 16
#define TT 360
#define VV 25
#define NN 9000
#define EE 72000
#define HH 128
#define RR (NN * BB)      // 144000 rows total
#define CROWS 18000       // rows per chunk (9000 nodes x 2 batches)
#define NT128 1125        // 128-row tiles (exact)
#define NPART0 563        // partial-stats blocks for k_mm2 (L0)
#define NCLSS 12
#define EPSB 1e-5f

// chunked activation layout: row R(n,b) = (b>>1)*CROWS + n*2 + (b&1)

typedef _Float16 h8v __attribute__((ext_vector_type(8)));
typedef float float16v __attribute__((ext_vector_type(16)));

__device__ __forceinline__ h8v cf8(unsigned packed) {
    uint4 cc = {packed, packed, packed, packed};
    return __builtin_bit_cast(h8v, cc);
}

// ---------------- graph preprocessing ----------------

__global__ void k_count(const int* __restrict__ ei, int* __restrict__ counts) {
    int e = blockIdx.x * 256 + threadIdx.x;
    if (e < EE) atomicAdd(&counts[ei[EE + e]], 1);
}

__global__ void k_dinv(const int* __restrict__ counts, float* __restrict__ dinv,
                       unsigned* __restrict__ d2p) {
    int n = blockIdx.x * 256 + threadIdx.x;
    if (n >= NN) return;
    float di = rsqrtf((float)(counts[n] + 1));
    dinv[n] = di;
    _Float16 d2 = (_Float16)(di * di);
    unsigned short u = __builtin_bit_cast(unsigned short, d2);
    d2p[n] = (unsigned)u | ((unsigned)u << 16);
}

__global__ void k_scan(const int* __restrict__ counts, int* __restrict__ rowptr4) {
    __shared__ int part[1024];
    int t = threadIdx.x;
    int base = t * 9;
    int loc[9];
    int s = 0;
#pragma unroll
    for (int i = 0; i < 9; i++) {
        int idx = base + i;
        int v = (idx < NN) ? ((counts[idx] + 3) & ~3) : 0;
        loc[i] = s;
        s += v;
    }
    part[t] = s;
    __syncthreads();
    for (int d = 1; d < 1024; d <<= 1) {
        int v = (t >= d) ? part[t - d] : 0;
        __syncthreads();
        part[t] += v;
        __syncthreads();
    }
    int excl = (t == 0) ? 0 : part[t - 1];
#pragma unroll
    for (int i = 0; i < 9; i++) {
        int idx = base + i;
        if (idx < NN) rowptr4[idx] = excl + loc[i];
    }
    if (t == 1023) rowptr4[NN] = part[1023];
}

__global__ void k_fill(const int* __restrict__ ei, const int* __restrict__ rowptr4,
                       int* __restrict__ cursor, const float* __restrict__ dinv,
                       int2* __restrict__ csr) {
    int e = blockIdx.x * 256 + threadIdx.x;
    if (e >= EE) return;
    int s = ei[e], d = ei[EE + e];
    int slot = rowptr4[d] + atomicAdd(&cursor[d], 1);
    _Float16 cfh = (_Float16)(dinv[s] * dinv[d]);
    unsigned short u = __builtin_bit_cast(unsigned short, cfh);
    int2 e2;
    e2.x = s;
    e2.y = (int)((unsigned)u | ((unsigned)u << 16));
    csr[slot] = e2;
}

__global__ void k_pad(const int* __restrict__ rowptr4, const int* __restrict__ cursor,
                      int2* __restrict__ csr) {
    int n = blockIdx.x * 256 + threadIdx.x;
    if (n >= NN) return;
    int beg = rowptr4[n] + cursor[n];
    int end = rowptr4[n + 1];
    int2 z;
    z.x = n;
    z.y = 0;
    for (int e = beg; e < end; e++) csr[e] = z;
}

// pre-convert the 11 layer weight matrices to f16 W^T images: Wh[l][c*128+k]
__global__ void k_wcvt(const float* __restrict__ sW, const float* __restrict__ mW,
                       const float* __restrict__ aW, _Float16* __restrict__ Wh) {
    int idx = blockIdx.x * 256 + threadIdx.x;
    if (idx >= 11 * 16384) return;
    int l = idx >> 14, r = idx & 16383;
    int k = r >> 7, c = r & 127;
    const float* src = (l < 2) ? sW + (size_t)l * 16384
                               : ((l == 2) ? mW : aW + (size_t)(l - 3) * 16384);
    Wh[(size_t)l * 16384 + c * 128 + k] = (_Float16)src[k * 128 + c];
}

// ---------------- L0 propagation of raw x (2 channels, f32) ----------------
__global__ void k_prop2(const float* __restrict__ x, float* __restrict__ P0,
                        const int* __restrict__ rowptr4, const int2* __restrict__ csr,
                        const float* __restrict__ dinv) {
    int n = blockIdx.x * 256 + threadIdx.x;
    if (n >= NN) return;
    int b = blockIdx.y;
    const float* xb = x + (size_t)b * NN * 2;
    float d2 = dinv[n] * dinv[n];
    float a0 = d2 * xb[2 * n], a1 = d2 * xb[2 * n + 1];
    int beg = rowptr4[n], end = rowptr4[n + 1];
    for (int j = beg; j < end; j++) {
        int2 e2 = csr[j];
        int s = e2.x;
        unsigned short u = (unsigned short)((unsigned)e2.y & 0xffffu);
        float cf = (float)__builtin_bit_cast(_Float16, u);
        a0 += cf * xb[2 * s];
        a1 += cf * xb[2 * s + 1];
    }
    float* Pb = P0 + (size_t)(n * BB + b) * 2;
    Pb[0] = a0;
    Pb[1] = a1;
}

// L0 matmul (K=2), writes chunked f16 layout, fused BN partial stats pS[c][part].
__global__ void __launch_bounds__(256) k_mm2(const float* __restrict__ P0,
                                             _Float16* __restrict__ A,
                                             const float* __restrict__ W,
                                             const float* __restrict__ bias,
                                             float* __restrict__ pS1, float* __restrict__ pS2) {
    __shared__ float L1[256][8], L2[256][8];
    int t = threadIdx.x;
    int cg = t & 15, c8 = cg * 8;
    float wv0[8], wv1[8], bv[8];
#pragma unroll
    for (int j = 0; j < 8; j++) {
        wv0[j] = W[c8 + j];
        wv1[j] = W[HH + c8 + j];
        bv[j] = bias[c8 + j];
    }
    float s1[8], s2[8];
#pragma unroll
    for (int j = 0; j < 8; j++) { s1[j] = 0.f; s2[j] = 0.f; }
    for (int idx = blockIdx.x * 256 + t; idx < RR * 16; idx += gridDim.x * 256) {
        int Rr = idx >> 4;
        int q = Rr / CROWS;
        int rr = Rr - q * CROWS;
        int n = rr >> 1;
        int b = q * 2 + (rr & 1);
        float p0 = P0[((size_t)n * BB + b) * 2], p1 = P0[((size_t)n * BB + b) * 2 + 1];
        h8v o;
#pragma unroll
        for (int j = 0; j < 8; j++) {
            float v = p0 * wv0[j] + p1 * wv1[j] + bv[j];
            s1[j] += v;
            s2[j] += v * v;
            o[j] = (_Float16)v;
        }
        *(h8v*)(A + (size_t)Rr * HH + c8) = o;
    }
#pragma unroll
    for (int j = 0; j < 8; j++) { L1[t][j] = s1[j]; L2[t][j] = s2[j]; }
    __syncthreads();
    if (t < 16) {
#pragma unroll
        for (int g = 1; g < 16; g++)
#pragma unroll
            for (int j = 0; j < 8; j++) {
                s1[j] = (g == 1 ? L1[t][j] : s1[j]) + L1[t + 16 * g][j];
                s2[j] = (g == 1 ? L2[t][j] : s2[j]) + L2[t + 16 * g][j];
            }
#pragma unroll
        for (int j = 0; j < 8; j++) {
            pS1[(size_t)(t * 8 + j) * NPART0 + blockIdx.x] = s1[j];
            pS2[(size_t)(t * 8 + j) * NPART0 + blockIdx.x] = s2[j];
        }
    }
}

// ---------------- activation pass: h' = relu(A*sc+sh), f16 -> f16 ----------------
__global__ void __launch_bounds__(256) k_act(const _Float16* __restrict__ A,
                                             _Float16* __restrict__ HP,
                                             const float* __restrict__ scale,
                                             const float* __restrict__ shiftv) {
    int i = blockIdx.x * 256 + threadIdx.x;
    int c8 = (i & 15) * 8;
    h8v v = *(const h8v*)(A + (size_t)i * 8);
    h8v o;
#pragma unroll
    for (int j = 0; j < 8; j++) {
        float f = (float)v[j] * scale[c8 + j] + shiftv[c8 + j];
        o[j] = (_Float16)fmaxf(f, 0.f);
    }
    *(h8v*)(HP + (size_t)i * 8) = o;
}

// ---------------- single-shift gather (trunk): P = A_hat * h' (round-13 proven) ----
__global__ void __launch_bounds__(256) k_gather1(const _Float16* __restrict__ h,
                                                 _Float16* __restrict__ Pz,
                                                 const int* __restrict__ rowptr4,
                                                 const int2* __restrict__ csr,
                                                 const unsigned* __restrict__ d2p) {
    int t = threadIdx.x;
    int q = blockIdx.x & 7;
    int ng4 = blockIdx.x >> 3;
    int wv = t >> 6, l = t & 63;
    int n = ng4 * 4 + wv;
    int half = l >> 5, li = l & 31;
    const _Float16* hb = h + (size_t)q * CROWS * HH + (size_t)li * 8;
    h8v acc;
    {
        h8v v = *(const h8v*)(hb + (size_t)n * 2 * HH);
        acc = v * cf8(half ? 0u : d2p[n]);
    }
    int beg = rowptr4[n], end = rowptr4[n + 1];
    int e = beg;
    for (; e + 8 <= end; e += 8) {
        int4 m0 = *(const int4*)(csr + e);
        int4 m1 = *(const int4*)(csr + e + 2);
        int4 m2 = *(const int4*)(csr + e + 4);
        int4 m3 = *(const int4*)(csr + e + 6);
        int s0 = half ? m0.z : m0.x;
        int s1 = half ? m1.z : m1.x;
        int s2 = half ? m2.z : m2.x;
        int s3 = half ? m3.z : m3.x;
        h8v v0 = *(const h8v*)(hb + (size_t)s0 * 2 * HH);
        h8v v1 = *(const h8v*)(hb + (size_t)s1 * 2 * HH);
        h8v v2 = *(const h8v*)(hb + (size_t)s2 * 2 * HH);
        h8v v3 = *(const h8v*)(hb + (size_t)s3 * 2 * HH);
        acc += v0 * cf8((unsigned)(half ? m0.w : m0.y));
        acc += v1 * cf8((unsigned)(half ? m1.w : m1.y));
        acc += v2 * cf8((unsigned)(half ? m2.w : m2.y));
        acc += v3 * cf8((unsigned)(half ? m3.w : m3.y));
    }
    if (e < end) {
        int4 m0 = *(const int4*)(csr + e);
        int4 m1 = *(const int4*)(csr + e + 2);
        int s0 = half ? m0.z : m0.x;
        int s1 = half ? m1.z : m1.x;
        h8v v0 = *(const h8v*)(hb + (size_t)s0 * 2 * HH);
        h8v v1 = *(const h8v*)(hb + (size_t)s1 * 2 * HH);
        acc += v0 * cf8((unsigned)(half ? m0.w : m0.y));
        acc += v1 * cf8((unsigned)(half ? m1.w : m1.y));
    }
    {
        int4 ai = __builtin_bit_cast(int4, acc);
        int4 bi4;
        bi4.x = __shfl_xor(ai.x, 32, 64);
        bi4.y = __shfl_xor(ai.y, 32, 64);
        bi4.z = __shfl_xor(ai.z, 32, 64);
        bi4.w = __shfl_xor(ai.w, 32, 64);
        acc += __builtin_bit_cast(h8v, bi4);
    }
    if (half == 0) {
        *(h8v*)(Pz + ((size_t)q * CROWS + (size_t)n * 2) * HH + (size_t)li * 8) = acc;
    }
}

// ---------------- combined 3-shift gather (heads): one edge sweep, 3 accumulators ----
// csr metadata read once; per edge 3 shifted rows loaded (6 loads in flight / iter).
__global__ void __launch_bounds__(256) k_gather3c(const _Float16* __restrict__ h,
                                                  _Float16* B0, _Float16* B1, _Float16* B2,
                                                  const int* __restrict__ rowptr4,
                                                  const int2* __restrict__ csr,
                                                  const unsigned* __restrict__ d2p,
                                                  int shbase) {
    int t = threadIdx.x;
    int q = blockIdx.x & 7;
    int ng4 = blockIdx.x >> 3;
    int wv = t >> 6, l = t & 63;
    int n = ng4 * 4 + wv;
    int half = l >> 5, li = l & 31;
    const _Float16* hb = h + (size_t)q * CROWS * HH + (size_t)li * 8;
    int sh0 = shbase, sh1 = shbase + 1000, sh2 = shbase + 2000;
    h8v acc0, acc1, acc2;
    {
        unsigned dp = half ? 0u : d2p[n];
        int p0 = n + sh0; if (p0 >= NN) p0 -= NN;
        int p1 = n + sh1; if (p1 >= NN) p1 -= NN;
        int p2 = n + sh2; if (p2 >= NN) p2 -= NN;
        h8v v0 = *(const h8v*)(hb + (size_t)p0 * 2 * HH);
        h8v v1 = *(const h8v*)(hb + (size_t)p1 * 2 * HH);
        h8v v2 = *(const h8v*)(hb + (size_t)p2 * 2 * HH);
        h8v dv = cf8(dp);
        acc0 = v0 * dv;
        acc1 = v1 * dv;
        acc2 = v2 * dv;
    }
    int beg = rowptr4[n], end = rowptr4[n + 1];
    for (int e = beg; e < end; e += 4) {
        int4 m0 = *(const int4*)(csr + e);      // edges e, e+1
        int4 m1 = *(const int4*)(csr + e + 2);  // edges e+2, e+3
        int sA = half ? m0.z : m0.x;            // this half's first edge
        int sB = half ? m1.z : m1.x;            // this half's second edge
        unsigned cA = (unsigned)(half ? m0.w : m0.y);
        unsigned cB = (unsigned)(half ? m1.w : m1.y);
        int a0 = sA + sh0; if (a0 >= NN) a0 -= NN;
        int a1 = sA + sh1; if (a1 >= NN) a1 -= NN;
        int a2 = sA + sh2; if (a2 >= NN) a2 -= NN;
        int b0 = sB + sh0; if (b0 >= NN) b0 -= NN;
        int b1 = sB + sh1; if (b1 >= NN) b1 -= NN;
        int b2 = sB + sh2; if (b2 >= NN) b2 -= NN;
        h8v vA0 = *(const h8v*)(hb + (size_t)a0 * 2 * HH);  // 6 loads in flight
        h8v vA1 = *(const h8v*)(hb + (size_t)a1 * 2 * HH);
        h8v vA2 = *(const h8v*)(hb + (size_t)a2 * 2 * HH);
        h8v vB0 = *(const h8v*)(hb + (size_t)b0 * 2 * HH);
        h8v vB1 = *(const h8v*)(hb + (size_t)b1 * 2 * HH);
        h8v vB2 = *(const h8v*)(hb + (size_t)b2 * 2 * HH);
        h8v fA = cf8(cA), fB = cf8(cB);
        acc0 += vA0 * fA;
        acc1 += vA1 * fA;
        acc2 += vA2 * fA;
        acc0 += vB0 * fB;
        acc1 += vB1 * fB;
        acc2 += vB2 * fB;
    }
    // combine even/odd-edge halves for each accumulator
#pragma unroll
    for (int z = 0; z < 3; z++) {
        h8v* ap = (z == 0) ? &acc0 : ((z == 1) ? &acc1 : &acc2);
        int4 ai = __builtin_bit_cast(int4, *ap);
        int4 bi4;
        bi4.x = __shfl_xor(ai.x, 32, 64);
        bi4.y = __shfl_xor(ai.y, 32, 64);
        bi4.z = __shfl_xor(ai.z, 32, 64);
        bi4.w = __shfl_xor(ai.w, 32, 64);
        *ap += __builtin_bit_cast(h8v, bi4);
    }
    if (half == 0) {
        size_t off = ((size_t)q * CROWS + (size_t)n * 2) * HH + (size_t)li * 8;
        *(h8v*)(B0 + off) = acc0;
        *(h8v*)(B1 + off) = acc1;
        *(h8v*)(B2 + off) = acc2;
    }
}

// ---------------- MFMA x NZ, IN-PLACE, 128-row blocks (dual 64-row tiles, shared W) ----
__global__ void __launch_bounds__(256) k_mfma3(_Float16* B0, _Float16* B1, _Float16* B2,
                                               const _Float16* __restrict__ Wh_g,
                                               const float* bias0, const float* bias1,
                                               const float* bias2,
                                               float* __restrict__ pS1,
                                               float* __restrict__ pS2) {
    __shared__ float rb1[4][128], rb2[4][128];  // 4 KB stats reduction
    int z = blockIdx.y;
    _Float16* B = (z == 0) ? B0 : ((z == 1) ? B1 : B2);
    const _Float16* Wh = Wh_g + (size_t)z * 16384;
    const float* bias = (z == 0) ? bias0 : ((z == 1) ? bias1 : bias2);
    int t = threadIdx.x;
    int w = t >> 6, l = t & 63;
    int rw = w >> 1, cw = w & 1;
    int lr = l & 31, hi = l >> 5;
    size_t rbase = (size_t)blockIdx.x * 128;
    const _Float16* Pr0 = B + (rbase + rw * 32 + lr) * HH;
    const _Float16* Pr1 = B + (rbase + 64 + rw * 32 + lr) * HH;
    const _Float16* Wc0 = Wh + (size_t)(cw * 64 + lr) * HH;
    const _Float16* Wc1 = Wh + (size_t)(cw * 64 + 32 + lr) * HH;
    float16v acc2[2][2];
#pragma unroll
    for (int rt = 0; rt < 2; rt++)
#pragma unroll
        for (int ct = 0; ct < 2; ct++) acc2[rt][ct] = (float16v)(0.0f);
#pragma unroll
    for (int ks = 0; ks < 8; ks++) {
        int koff = ks * 16 + hi * 8;
        h8v a0 = *(const h8v*)(Pr0 + koff);
        h8v a1 = *(const h8v*)(Pr1 + koff);
        h8v b0 = *(const h8v*)(Wc0 + koff);
        h8v b1 = *(const h8v*)(Wc1 + koff);
        acc2[0][0] = __builtin_amdgcn_mfma_f32_32x32x16_f16(a0, b0, acc2[0][0], 0, 0, 0);
        acc2[0][1] = __builtin_amdgcn_mfma_f32_32x32x16_f16(a0, b1, acc2[0][1], 0, 0, 0);
        acc2[1][0] = __builtin_amdgcn_mfma_f32_32x32x16_f16(a1, b0, acc2[1][0], 0, 0, 0);
        acc2[1][1] = __builtin_amdgcn_mfma_f32_32x32x16_f16(a1, b1, acc2[1][1], 0, 0, 0);
    }
    __syncthreads();  // drain all waves' reads of this 128-row block before overwrite
    float bv[2] = {bias[cw * 64 + lr], bias[cw * 64 + 32 + lr]};
    float s1a[2] = {0.f, 0.f}, s2a[2] = {0.f, 0.f};
#pragma unroll
    for (int rt = 0; rt < 2; rt++)
#pragma unroll
        for (int ct = 0; ct < 2; ct++) {
            int c = cw * 64 + ct * 32 + lr;
#pragma unroll
            for (int g = 0; g < 16; g++) {
                int row = rt * 64 + rw * 32 + (g & 3) + 8 * (g >> 2) + 4 * hi;
                float v = acc2[rt][ct][g] + bv[ct];
                s1a[ct] += v;
                s2a[ct] += v * v;
                B[(rbase + row) * HH + c] = (_Float16)v;
            }
        }
    int slot = rw * 2 + hi;
#pragma unroll
    for (int ct = 0; ct < 2; ct++) {
        int cidx = cw * 64 + ct * 32 + lr;
        rb1[slot][cidx] = s1a[ct];
        rb2[slot][cidx] = s2a[ct];
    }
    __syncthreads();
    if (t < 128) {
        float a1 = rb1[0][t] + rb1[1][t] + rb1[2][t] + rb1[3][t];
        float a2 = rb2[0][t] + rb2[1][t] + rb2[2][t] + rb2[3][t];
        pS1[((size_t)z * HH + t) * NT128 + blockIdx.x] = a1;
        pS2[((size_t)z * HH + t) * NT128 + blockIdx.x] = a2;
    }
}

// finalize BN affine from transposed partials, grid = NZ*128 blocks
__global__ void __launch_bounds__(256) k_bnfin3(const float* __restrict__ pS1,
                                                const float* __restrict__ pS2, int npart,
                                                const float* g0, const float* g1,
                                                const float* g2, const float* be0,
                                                const float* be1, const float* be2,
                                                float* __restrict__ scale,
                                                float* __restrict__ shiftv) {
    __shared__ float R1[256], R2[256];
    int z = blockIdx.x >> 7, c = blockIdx.x & 127;
    const float* g = (z == 0) ? g0 : ((z == 1) ? g1 : g2);
    const float* be = (z == 0) ? be0 : ((z == 1) ? be1 : be2);
    int t = threadIdx.x;
    const float* p1 = pS1 + ((size_t)z * HH + c) * npart;
    const float* p2 = pS2 + ((size_t)z * HH + c) * npart;
    float s1 = 0.f, s2 = 0.f;
    for (int i = t; i < npart; i += 256) {
        s1 += p1[i];
        s2 += p2[i];
    }
    R1[t] = s1;
    R2[t] = s2;
    __syncthreads();
    for (int d = 128; d > 0; d >>= 1) {
        if (t < d) {
            R1[t] += R1[t + d];
            R2[t] += R2[t + d];
        }
        __syncthreads();
    }
    if (t == 0) {
        float inv = 1.0f / (float)RR;
        float mu = R1[0] * inv;
        float var = R2[0] * inv - mu * mu;
        float sc = g[c] * rsqrtf(var + EPSB);
        scale[z * HH + c] = sc;
        shiftv[z * HH + c] = be[c] - mu * sc;
    }
}

// fused BN-affine + ReLU + mean-pool x3 heads: grid (36, BB, 3)
__global__ void __launch_bounds__(256) k_pool3(const _Float16* B0, const _Float16* B1,
                                               const _Float16* B2,
                                               const float* __restrict__ scale,
                                               const float* __restrict__ shiftv,
                                               float* __restrict__ pooled) {
    __shared__ float L[256][8];
    int z = blockIdx.z;
    const _Float16* A = (z == 0) ? B0 : ((z == 1) ? B1 : B2);
    const float* sc0 = scale + z * HH;
    const float* sh0 = shiftv + z * HH;
    float* pz = pooled + (size_t)z * BB * HH;
    int t = threadIdx.x;
    int b = blockIdx.y;
    int n0 = blockIdx.x * 250;
    int ng = t >> 4, c8 = (t & 15) * 8;
    float sc[8], sh[8];
#pragma unroll
    for (int j = 0; j < 8; j++) {
        sc[j] = sc0[c8 + j];
        sh[j] = sh0[c8 + j];
    }
    const _Float16* Ab = A + ((size_t)(b >> 1) * CROWS + (b & 1)) * HH;
    float acc[8];
#pragma unroll
    for (int j = 0; j < 8; j++) acc[j] = 0.f;
    for (int n = n0 + ng; n < n0 + 250; n += 16) {
        h8v v = *(const h8v*)(Ab + (size_t)n * 2 * HH + c8);
#pragma unroll
        for (int j = 0; j < 8; j++) {
            float f = (float)v[j] * sc[j] + sh[j];
            acc[j] += fmaxf(f, 0.f);
        }
    }
#pragma unroll
    for (int j = 0; j < 8; j++) L[t][j] = acc[j];
    __syncthreads();
    if (ng == 0) {
#pragma unroll
        for (int g = 1; g < 16; g++)
#pragma unroll
            for (int j = 0; j < 8; j++) acc[j] += L[t + 16 * g][j];
#pragma unroll
        for (int j = 0; j < 8; j++) atomicAdd(&pz[b * HH + t * 8 + j], acc[j]);
    }
}

// all 9 heads: linear + log_softmax
__global__ void __launch_bounds__(192) k_head_all(const float* __restrict__ pooled,
                                                  const float* __restrict__ main_Wf,
                                                  const float* __restrict__ main_bf,
                                                  const float* __restrict__ aux_Wf,
                                                  const float* __restrict__ aux_bf,
                                                  float* __restrict__ out) {
    int hd = blockIdx.x;
    const float* Wf = hd ? aux_Wf + (size_t)(hd - 1) * HH * NCLSS : main_Wf;
    const float* bf = hd ? aux_bf + (hd - 1) * NCLSS : main_bf;
    const float* pl = pooled + (size_t)hd * BB * HH;
    __shared__ float z[BB][NCLSS];
    __shared__ float lse[BB];
    int t = threadIdx.x;
    int b = t / NCLSS, j = t % NCLSS;
    if (t < BB * NCLSS) {
        float acc = bf[j];
        const float invn = 1.0f / NN;
        for (int c = 0; c < HH; c++) acc += pl[b * HH + c] * invn * Wf[c * NCLSS + j];
        z[b][j] = acc;
    }
    __syncthreads();
    if (t < BB) {
        float m = -1e30f;
        for (int j2 = 0; j2 < NCLSS; j2++) m = fmaxf(m, z[t][j2]);
        float s = 0.f;
        for (int j2 = 0; j2 < NCLSS; j2++) s += expf(z[t][j2] - m);
        lse[t] = m + logf(s);
    }
    __syncthreads();
    if (t < BB * NCLSS) {
        float* o = hd ? out + BB * NCLSS + ((size_t)b * 8 + (hd - 1)) * NCLSS + j
                      : out + b * NCLSS + j;
        *o = z[b][j] - lse[b];
    }
}

// ---------------- host ----------------

extern "C" void kernel_launch(void* const* d_in, const int* in_sizes, int n_in, void* d_out,
                              int out_size, void* d_ws, size_t ws_size, hipStream_t stream) {
    const float* x = (const float*)d_in[0];
    const int* ei = (const int*)d_in[1];
    const float* W_in = (const float*)d_in[2];
    const float* b_in = (const float*)d_in[3];
    const float* g_in = (const float*)d_in[4];
    const float* be_in = (const float*)d_in[5];
    const float* shared_W = (const float*)d_in[6];
    const float* shared_b = (const float*)d_in[7];
    const float* shared_g = (const float*)d_in[8];
    const float* shared_be = (const float*)d_in[9];
    const float* main_Wg = (const float*)d_in[10];
    const float* main_bg = (const float*)d_in[11];
    const float* main_g = (const float*)d_in[12];
    const float* main_be = (const float*)d_in[13];
    const float* main_Wf = (const float*)d_in[14];
    const float* main_bf = (const float*)d_in[15];
    const float* aux_Wg = (const float*)d_in[16];
    const float* aux_bg = (const float*)d_in[17];
    const float* aux_g = (const float*)d_in[18];
    const float* aux_be = (const float*)d_in[19];
    const float* aux_Wf = (const float*)d_in[20];
    const float* aux_bf = (const float*)d_in[21];
    float* out = (float*)d_out;

    char* w = (char*)d_ws;
    const size_t BIG = (size_t)RR * HH * 2;
    _Float16* U = (_Float16*)w;  w += BIG;
    _Float16* V = (_Float16*)w;  w += BIG;
    _Float16* P = (_Float16*)w;  w += BIG;
    _Float16* HP = (_Float16*)w; w += BIG;
    float* P0 = (float*)w;       w += (size_t)RR * 2 * 4;
    _Float16* Wh = (_Float16*)w; w += (size_t)11 * 16384 * 2;
    int2* csr = (int2*)w;        w += (size_t)102400 * 8;
    int* counts = (int*)w;       w += NN * 4;
    int* cursor = (int*)w;       w += NN * 4;
    float* dinv = (float*)w;     w += NN * 4;
    unsigned* d2p = (unsigned*)w; w += NN * 4;
    int* rowptr4 = (int*)w;      w += 36016;
    float* pS1 = (float*)w;      w += (size_t)3 * HH * NT128 * 4;
    float* pS2 = (float*)w;      w += (size_t)3 * HH * NT128 * 4;
    float* pooled = (float*)w;   w += 9 * BB * HH * 4;
    float* tscale = (float*)w;   w += 512;
    float* tshift = (float*)w;   w += 512;
    float* hscale = (float*)w;   w += 2048;
    float* hshift = (float*)w;   w += 2048;

    hipMemsetAsync(counts, 0, 2 * NN * 4, stream);
    hipMemsetAsync(pooled, 0, 9 * BB * HH * 4, stream);

    k_count<<<(EE + 255) / 256, 256, 0, stream>>>(ei, counts);
    k_dinv<<<(NN + 255) / 256, 256, 0, stream>>>(counts, dinv, d2p);
    k_scan<<<1, 1024, 0, stream>>>(counts, rowptr4);
    k_fill<<<(EE + 255) / 256, 256, 0, stream>>>(ei, rowptr4, cursor, dinv, csr);
    k_pad<<<(NN + 255) / 256, 256, 0, stream>>>(rowptr4, cursor, csr);
    k_wcvt<<<(11 * 16384 + 255) / 256, 256, 0, stream>>>(shared_W, main_Wg, aux_Wg, Wh);

    // L0: prop x, K=2 matmul -> U (pre-BN), stats -> tscale/tshift
    {
        dim3 g((NN + 255) / 256, BB);
        k_prop2<<<g, 256, 0, stream>>>(x, P0, rowptr4, csr, dinv);
        k_mm2<<<NPART0, 256, 0, stream>>>(P0, U, W_in, b_in, pS1, pS2);
        k_bnfin3<<<HH, 256, 0, stream>>>(pS1, pS2, NPART0, g_in, g_in, g_in, be_in, be_in,
                                         be_in, tscale, tshift);
    }

    // trunk layer 0: act(U->HP), gather(HP->V), mfma in-place (V), bnfin
    k_act<<<RR * 16 / 256, 256, 0, stream>>>(U, HP, tscale, tshift);
    k_gather1<<<8 * 2250, 256, 0, stream>>>(HP, V, rowptr4, csr, d2p);
    k_mfma3<<<dim3(NT128, 1), 256, 0, stream>>>(V, V, V, Wh, shared_b, shared_b, shared_b,
                                                pS1, pS2);
    k_bnfin3<<<HH, 256, 0, stream>>>(pS1, pS2, NT128, shared_g, shared_g, shared_g, shared_be,
                                     shared_be, shared_be, tscale, tshift);
    // trunk layer 1: act(V->HP), gather(HP->U), mfma in-place (U), bnfin
    k_act<<<RR * 16 / 256, 256, 0, stream>>>(V, HP, tscale, tshift);
    k_gather1<<<8 * 2250, 256, 0, stream>>>(HP, U, rowptr4, csr, d2p);
    k_mfma3<<<dim3(NT128, 1), 256, 0, stream>>>(U, U, U, Wh + 16384, shared_b + HH,
                                                shared_b + HH, shared_b + HH, pS1, pS2);
    k_bnfin3<<<HH, 256, 0, stream>>>(pS1, pS2, NT128, shared_g + HH, shared_g + HH,
                                     shared_g + HH, shared_be + HH, shared_be + HH,
                                     shared_be + HH, tscale, tshift);
    // trunk output activation (shared by all 9 heads)
    k_act<<<RR * 16 / 256, 256, 0, stream>>>(U, HP, tscale, tshift);

    // heads in 3 groups of 3: one combined edge sweep fills {P,U,V}; then mfma+pool
    for (int g = 0; g < 3; g++) {
        int h0 = g * 3;
        const float* bg[3];
        const float* gg[3];
        const float* be[3];
        for (int z = 0; z < 3; z++) {
            int hd = h0 + z;
            bg[z] = (hd == 0) ? main_bg : aux_bg + (hd - 1) * HH;
            gg[z] = (hd == 0) ? main_g : aux_g + (hd - 1) * HH;
            be[z] = (hd == 0) ? main_be : aux_be + (hd - 1) * HH;
        }
        k_gather3c<<<8 * 2250, 256, 0, stream>>>(HP, P, U, V, rowptr4, csr, d2p, h0 * 1000);
        k_mfma3<<<dim3(NT128, 3), 256, 0, stream>>>(P, U, V, Wh + (size_t)(2 + h0) * 16384,
                                                    bg[0], bg[1], bg[2], pS1, pS2);
        k_bnfin3<<<3 * HH, 256, 0, stream>>>(pS1, pS2, NT128, gg[0], gg[1], gg[2], be[0],
                                             be[1], be[2], hscale, hshift);
        k_pool3<<<dim3(36, BB, 3), 256, 0, stream>>>(P, U, V, hscale, hshift,
                                                     pooled + (size_t)h0 * BB * HH);
    }
    k_head_all<<<9, 192, 0, stream>>>(pooled, main_Wf, main_bf, aux_Wf, aux_bf, out);
}